// Round 1
// baseline (1094.886 us; speedup 1.0000x reference)
//
#include <hip/hip_runtime.h>
#include <hip/hip_bf16.h>

#define DN 100000     // N entities
#define DD 128        // D
#define DR 12         // R relations
#define DNB 8         // bases
#define DE 1000000    // edges
#define DP 400000     // hyperedge incidences
#define DHE 20000     // hyperedges
#define DHE2 40000    // both sides combined
#define DB 64         // batch
#define DLR 64
#define DLC 32
#define DNH 8
#define DHD 16
#define NRBINS (DR * DN)   // 1.2M
#define SCAN_CHUNK 1024
#define MCAP 65536

typedef unsigned short ushortT;
typedef unsigned int uintT;
typedef __attribute__((ext_vector_type(8))) short s8v;
typedef __attribute__((ext_vector_type(4))) float f4v;

#define APAD 136   // 64 rows of K=128 bf16, stride 272B

__device__ __forceinline__ ushortT rneb(float v) {
    uintT b = __float_as_uint(v);
    return (ushortT)((b + 0x7FFFu + ((b >> 16) & 1u)) >> 16);
}
__device__ __forceinline__ float b2f(ushortT h) {
    return __uint_as_float(((uintT)h) << 16);
}

__device__ __forceinline__ void split_store8(ushortT* hbase, ushortT* lbase, const float* v)
{
    ushortT h[8], l[8];
    #pragma unroll
    for (int j = 0; j < 8; ++j) {
        h[j] = rneb(v[j]);
        l[j] = rneb(v[j] - b2f(h[j]));
    }
    uint4 hv = make_uint4((uintT)h[0] | ((uintT)h[1] << 16), (uintT)h[2] | ((uintT)h[3] << 16),
                          (uintT)h[4] | ((uintT)h[5] << 16), (uintT)h[6] | ((uintT)h[7] << 16));
    uint4 lv = make_uint4((uintT)l[0] | ((uintT)l[1] << 16), (uintT)l[2] | ((uintT)l[3] << 16),
                          (uintT)l[4] | ((uintT)l[5] << 16), (uintT)l[6] | ((uintT)l[7] << 16));
    *(uint4*)hbase = hv;
    *(uint4*)lbase = lv;
}

// ---------------------------------------------------------------- weight pre-split (blocked fragment layout)
// WB[kc][n][k] (k in [0,32), n in [0,N)) ushort, h plane then l plane at +4*N*32.
// element value = trans ? W[n*128 + kc*32+k] : W[(kc*32+k)*128 + n]

// 9 static 128x128 matrices in one launch:
// 0 root(t0) 1 sess_theta(t0) 2 know_theta(t0) 3 wq(t1) 4 wk(t1) 5 wv(t1)
// 6 out_proj(t1) 7 attn_his_a(t0) 8 attn_a(t0)
__global__ __launch_bounds__(256) void k_presplit_all(
    const float* __restrict__ root, const float* __restrict__ st,
    const float* __restrict__ kt, const float* __restrict__ ipw,
    const float* __restrict__ opw, const float* __restrict__ aha,
    const float* __restrict__ aa, ushortT* __restrict__ outA)
{
    int gid = blockIdx.x * 256 + threadIdx.x;   // 9*16384 exact
    int mat = gid >> 14, e = gid & 16383;
    const float* srcs[9] = {root, st, kt, ipw, ipw + 16384, ipw + 32768, opw, aha, aa};
    const float* W = srcs[mat];
    bool t1 = (mat >= 3 && mat <= 6);
    int k = e & 31, n = (e >> 5) & 127, kc = e >> 12;
    float f = t1 ? W[(size_t)n * 128 + kc * 32 + k] : W[(size_t)(kc * 32 + k) * 128 + n];
    ushortT h = rneb(f);
    outA[(size_t)mat * 32768 + e] = h;
    outA[(size_t)mat * 32768 + 16384 + e] = rneb(f - b2f(h));
}

// user (64x128, trans=1): N=64, l plane at +8192
__global__ void k_presplit_user(const float* __restrict__ W, ushortT* __restrict__ o)
{
    int e = blockIdx.x * 256 + threadIdx.x;  // 4*64*32 = 8192 exact
    int k = e & 31, n = (e >> 5) & 63, kc = e >> 11;
    float f = W[(size_t)n * 128 + kc * 32 + k];
    ushortT h = rneb(f);
    o[e] = h;
    o[8192 + e] = rneb(f - b2f(h));
}

// w[r] = comp[r]·bases, split directly into blocked layout (64KB per r: h 32KB, l 32KB)
__global__ void k_wcomp_split(const float* __restrict__ comp, const float* __restrict__ bases,
                              ushortT* __restrict__ warena)
{
    int i = blockIdx.x * blockDim.x + threadIdx.x;
    if (i >= DR * DD * DD) return;
    int r = i / (DD * DD), io = i % (DD * DD);
    float s = 0.f;
    #pragma unroll
    for (int b = 0; b < DNB; ++b) s += comp[r * DNB + b] * bases[(size_t)b * DD * DD + io];
    int irow = io >> 7, o = io & 127;          // w[r][irow][o], irow = k-dim
    int kc = irow >> 5, k = irow & 31;
    size_t dst = (size_t)r * 32768 + (size_t)kc * 4096 + o * 32 + k;
    ushortT h = rneb(s);
    warena[dst] = h;
    warena[dst + 16384] = rneb(s - b2f(h));
}

// ---------------------------------------------------------------- MFMA GEMM, B fragments direct from pre-split global
__global__ __launch_bounds__(256) void k_gemm_ds(
    const float* __restrict__ A, const ushortT* __restrict__ Wb,
    const float* __restrict__ bias, const float* __restrict__ rs,
    float* __restrict__ C, int M)
{
    __shared__ __align__(16) ushortT Ah[64 * APAD], Al[64 * APAD];
    int tid = threadIdx.x;
    int row0 = blockIdx.x * 64;
    {
        int row = tid >> 2, c0 = (tid & 3) * 32;
        int gr = row0 + row;
        const float* ar = A + (size_t)gr * 128 + c0;
        float sc = 1.0f;
        if (rs && gr < M) { float d = rs[gr]; sc = (d > 0.f) ? 1.0f / d : 0.f; }
        #pragma unroll
        for (int g = 0; g < 4; ++g) {
            float v[8] = {};
            if (gr < M) {
                float4 u0 = *(const float4*)(ar + g * 8);
                float4 u1 = *(const float4*)(ar + g * 8 + 4);
                v[0]=u0.x*sc; v[1]=u0.y*sc; v[2]=u0.z*sc; v[3]=u0.w*sc;
                v[4]=u1.x*sc; v[5]=u1.y*sc; v[6]=u1.z*sc; v[7]=u1.w*sc;
            }
            split_store8(&Ah[row * APAD + c0 + g * 8], &Al[row * APAD + c0 + g * 8], v);
        }
    }
    __syncthreads();
    f4v acc[8] = {};
    int w = tid >> 6, lane = tid & 63, m = lane & 15, quad = lane >> 4;
    const ushortT* Wl = Wb + 16384;
    #pragma unroll
    for (int kc = 0; kc < 4; ++kc) {
        s8v ah = *(const s8v*)&Ah[(w * 16 + m) * APAD + kc * 32 + quad * 8];
        s8v al = *(const s8v*)&Al[(w * 16 + m) * APAD + kc * 32 + quad * 8];
        #pragma unroll
        for (int nt = 0; nt < 8; ++nt) {
            size_t boff = ((size_t)kc * 128 + nt * 16 + m) * 32 + quad * 8;
            s8v bh = *(const s8v*)&Wb[boff];
            s8v bl = *(const s8v*)&Wl[boff];
            acc[nt] = __builtin_amdgcn_mfma_f32_16x16x32_bf16(ah, bh, acc[nt], 0, 0, 0);
            acc[nt] = __builtin_amdgcn_mfma_f32_16x16x32_bf16(al, bh, acc[nt], 0, 0, 0);
            acc[nt] = __builtin_amdgcn_mfma_f32_16x16x32_bf16(ah, bl, acc[nt], 0, 0, 0);
        }
    }
    float bv[8];
    #pragma unroll
    for (int nt = 0; nt < 8; ++nt) bv[nt] = bias ? bias[nt * 16 + m] : 0.f;
    #pragma unroll
    for (int rr = 0; rr < 4; ++rr) {
        int gr = row0 + w * 16 + quad * 4 + rr;
        if (gr < M) {
            #pragma unroll
            for (int nt = 0; nt < 8; ++nt)
                C[(size_t)gr * 128 + nt * 16 + m] = acc[nt][rr] + bv[nt];
        }
    }
}

// ---------------------------------------------------------------- fused e[row] = tanh(A@W)[row,:] . bvec
__global__ __launch_bounds__(256) void k_tanh_dot_ds(
    const float* __restrict__ A, const ushortT* __restrict__ Wb,
    const float* __restrict__ bvec, float* __restrict__ e, int M)
{
    __shared__ __align__(16) ushortT Ah[64 * APAD], Al[64 * APAD];
    int tid = threadIdx.x;
    int row0 = blockIdx.x * 64;
    {
        int row = tid >> 2, c0 = (tid & 3) * 32;
        int gr = row0 + row;
        const float* ar = A + (size_t)gr * 128 + c0;
        #pragma unroll
        for (int g = 0; g < 4; ++g) {
            float v[8] = {};
            if (gr < M) {
                float4 u0 = *(const float4*)(ar + g * 8);
                float4 u1 = *(const float4*)(ar + g * 8 + 4);
                v[0]=u0.x; v[1]=u0.y; v[2]=u0.z; v[3]=u0.w;
                v[4]=u1.x; v[5]=u1.y; v[6]=u1.z; v[7]=u1.w;
            }
            split_store8(&Ah[row * APAD + c0 + g * 8], &Al[row * APAD + c0 + g * 8], v);
        }
    }
    __syncthreads();
    f4v acc[8] = {};
    int w = tid >> 6, lane = tid & 63, m = lane & 15, quad = lane >> 4;
    const ushortT* Wl = Wb + 16384;
    #pragma unroll
    for (int kc = 0; kc < 4; ++kc) {
        s8v ah = *(const s8v*)&Ah[(w * 16 + m) * APAD + kc * 32 + quad * 8];
        s8v al = *(const s8v*)&Al[(w * 16 + m) * APAD + kc * 32 + quad * 8];
        #pragma unroll
        for (int nt = 0; nt < 8; ++nt) {
            size_t boff = ((size_t)kc * 128 + nt * 16 + m) * 32 + quad * 8;
            s8v bh = *(const s8v*)&Wb[boff];
            s8v bl = *(const s8v*)&Wl[boff];
            acc[nt] = __builtin_amdgcn_mfma_f32_16x16x32_bf16(ah, bh, acc[nt], 0, 0, 0);
            acc[nt] = __builtin_amdgcn_mfma_f32_16x16x32_bf16(al, bh, acc[nt], 0, 0, 0);
            acc[nt] = __builtin_amdgcn_mfma_f32_16x16x32_bf16(ah, bl, acc[nt], 0, 0, 0);
        }
    }
    float bv[8];
    #pragma unroll
    for (int nt = 0; nt < 8; ++nt) bv[nt] = bvec[nt * 16 + m];
    #pragma unroll
    for (int rr = 0; rr < 4; ++rr) {
        float p = 0.f;
        #pragma unroll
        for (int nt = 0; nt < 8; ++nt) p += tanhf(acc[nt][rr]) * bv[nt];
        #pragma unroll
        for (int o = 1; o < 16; o <<= 1) p += __shfl_xor(p, o);
        int gr = row0 + w * 16 + quad * 4 + rr;
        if (m == 0 && gr < M) e[gr] = p;
    }
}

// ---------------------------------------------------------------- softmax(e) weighted sum of h rows
template <int L>
__global__ __launch_bounds__(128) void k_pool_apply(const float* __restrict__ h,
                                                    const float* __restrict__ e,
                                                    float* __restrict__ out)
{
    __shared__ float es[L];
    int b = blockIdx.x, tid = threadIdx.x;
    if (tid < L) es[tid] = e[b * L + tid];
    __syncthreads();
    float mx = -1e30f;
    #pragma unroll
    for (int l = 0; l < L; ++l) mx = fmaxf(mx, es[l]);
    float wgt[L];
    float sum = 0.f;
    #pragma unroll
    for (int l = 0; l < L; ++l) { wgt[l] = __expf(es[l] - mx); sum += wgt[l]; }
    float inv = 1.0f / sum;
    float o = 0.f;
    #pragma unroll
    for (int l = 0; l < L; ++l) o += wgt[l] * h[((size_t)b * L + l) * 128 + tid];
    out[(size_t)b * 128 + tid] = o * inv;
}

__global__ void k_build_ucat(const float* __restrict__ ctx, const float* __restrict__ his,
                             float* ucat)
{
    int i = blockIdx.x * blockDim.x + threadIdx.x;
    if (i >= DB * 33 * 128) return;
    int d = i & 127, l = (i >> 7) % 33, b = i / (33 * 128);
    ucat[i] = (l < 32) ? ctx[((size_t)b * 32 + l) * 128 + d] : his[(size_t)b * 128 + d];
}

// ---------------------------------------------------------------- RGCN fused segment-mean @ w[r] -> kg += (MFMA, direct-B)
__global__ __launch_bounds__(256) void k_rgcn_ds(
    const float* __restrict__ x, const ushortT* __restrict__ warena,
    const int* __restrict__ seglist, const int* __restrict__ soff,
    const int* __restrict__ slen, const int* __restrict__ ssrc,
    const int* __restrict__ stypebase, float* __restrict__ kg, int r)
{
    __shared__ __align__(16) ushortT Ah[64 * APAD], Al[64 * APAD];
    int s0 = stypebase[r], s1 = stypebase[r + 1];
    int base = s0 + blockIdx.x * 64;
    if (base >= s1) return;
    int nrow = min(64, s1 - base);
    int tid = threadIdx.x;
    const ushortT* Wb = warena + (size_t)r * 32768;
    const ushortT* Wl = Wb + 16384;
    {
        int row = tid >> 2, c0 = (tid & 3) * 32;
        float a[32] = {};
        if (row < nrow) {
            int key = seglist[base + row];
            int st = soff[key], len = slen[key];
            for (int i = 0; i < len; ++i) {
                const float* xr = x + (size_t)ssrc[st + i] * 128 + c0;
                #pragma unroll
                for (int j = 0; j < 8; ++j) {
                    float4 v = *(const float4*)(xr + j * 4);
                    a[j*4+0] += v.x; a[j*4+1] += v.y; a[j*4+2] += v.z; a[j*4+3] += v.w;
                }
            }
            float inv = 1.0f / (float)max(len, 1);
            #pragma unroll
            for (int j = 0; j < 32; ++j) a[j] *= inv;
        }
        #pragma unroll
        for (int g = 0; g < 4; ++g)
            split_store8(&Ah[row * APAD + c0 + g * 8], &Al[row * APAD + c0 + g * 8], a + g * 8);
    }
    __syncthreads();
    f4v acc[8] = {};
    int w = tid >> 6, lane = tid & 63, m = lane & 15, quad = lane >> 4;
    #pragma unroll
    for (int kc = 0; kc < 4; ++kc) {
        s8v ah = *(const s8v*)&Ah[(w * 16 + m) * APAD + kc * 32 + quad * 8];
        s8v al = *(const s8v*)&Al[(w * 16 + m) * APAD + kc * 32 + quad * 8];
        #pragma unroll
        for (int nt = 0; nt < 8; ++nt) {
            size_t boff = ((size_t)kc * 128 + nt * 16 + m) * 32 + quad * 8;
            s8v bh = *(const s8v*)&Wb[boff];
            s8v bl = *(const s8v*)&Wl[boff];
            acc[nt] = __builtin_amdgcn_mfma_f32_16x16x32_bf16(ah, bh, acc[nt], 0, 0, 0);
            acc[nt] = __builtin_amdgcn_mfma_f32_16x16x32_bf16(al, bh, acc[nt], 0, 0, 0);
            acc[nt] = __builtin_amdgcn_mfma_f32_16x16x32_bf16(ah, bl, acc[nt], 0, 0, 0);
        }
    }
    #pragma unroll
    for (int rr = 0; rr < 4; ++rr) {
        int rt = w * 16 + quad * 4 + rr;
        if (rt < nrow) {
            int dst = seglist[base + rt] - r * DN;
            float* kr = kg + (size_t)dst * 128 + m;
            #pragma unroll
            for (int nt = 0; nt < 8; ++nt)
                kr[nt * 16] += acc[nt][rr];
        }
    }
}

// ---------------------------------------------------------------- scoring (MFMA, direct-B from pre-split user)
__global__ __launch_bounds__(256) void k_score_ds(
    const float* __restrict__ kg, const ushortT* __restrict__ Ub,
    const float* __restrict__ rb, float* __restrict__ out)
{
    __shared__ __align__(16) ushortT Ah[64 * APAD], Al[64 * APAD];
    int tid = threadIdx.x;
    int n0 = blockIdx.x * 64;
    {
        int row = tid >> 2, c0 = (tid & 3) * 32;
        int gr = n0 + row;
        const float* ar = kg + (size_t)gr * 128 + c0;
        #pragma unroll
        for (int g = 0; g < 4; ++g) {
            float v[8] = {};
            if (gr < DN) {
                float4 u0 = *(const float4*)(ar + g * 8);
                float4 u1 = *(const float4*)(ar + g * 8 + 4);
                v[0]=u0.x; v[1]=u0.y; v[2]=u0.z; v[3]=u0.w;
                v[4]=u1.x; v[5]=u1.y; v[6]=u1.z; v[7]=u1.w;
            }
            split_store8(&Ah[row * APAD + c0 + g * 8], &Al[row * APAD + c0 + g * 8], v);
        }
    }
    __syncthreads();
    f4v acc[4] = {};
    int w = tid >> 6, lane = tid & 63, m = lane & 15, quad = lane >> 4;
    const ushortT* Ul = Ub + 8192;
    #pragma unroll
    for (int kc = 0; kc < 4; ++kc) {
        s8v ah = *(const s8v*)&Ah[(w * 16 + m) * APAD + kc * 32 + quad * 8];
        s8v al = *(const s8v*)&Al[(w * 16 + m) * APAD + kc * 32 + quad * 8];
        #pragma unroll
        for (int nt = 0; nt < 4; ++nt) {
            size_t boff = ((size_t)kc * 64 + nt * 16 + m) * 32 + quad * 8;
            s8v bh = *(const s8v*)&Ub[boff];
            s8v bl = *(const s8v*)&Ul[boff];
            acc[nt] = __builtin_amdgcn_mfma_f32_16x16x32_bf16(ah, bh, acc[nt], 0, 0, 0);
            acc[nt] = __builtin_amdgcn_mfma_f32_16x16x32_bf16(al, bh, acc[nt], 0, 0, 0);
            acc[nt] = __builtin_amdgcn_mfma_f32_16x16x32_bf16(ah, bl, acc[nt], 0, 0, 0);
        }
    }
    int n = n0 + w * 16 + quad * 4;
    if (n < DN) {
        float4 rbv = *(const float4*)&rb[n];
        #pragma unroll
        for (int nt = 0; nt < 4; ++nt) {
            int b = nt * 16 + m;
            float4 o = make_float4(acc[nt][0] + rbv.x, acc[nt][1] + rbv.y,
                                   acc[nt][2] + rbv.z, acc[nt][3] + rbv.w);
            *(float4*)&out[(size_t)b * DN + n] = o;
        }
    }
}

// ---------------------------------------------------------------- scans (single-mode, for hyper)
__global__ void k_scan_pass1(const int* __restrict__ in, int n, int* __restrict__ bsum)
{
    __shared__ int red[256];
    int b = blockIdx.x, t = threadIdx.x;
    int i0 = b * SCAN_CHUNK + t * 4;
    int s = 0;
    #pragma unroll
    for (int j = 0; j < 4; ++j) {
        int i = i0 + j;
        if (i < n) s += in[i];
    }
    red[t] = s;
    __syncthreads();
    for (int o = 128; o > 0; o >>= 1) {
        if (t < o) red[t] += red[t + o];
        __syncthreads();
    }
    if (t == 0) bsum[b] = red[0];
}

__global__ __launch_bounds__(256) void k_scan_pass2p(int* bsum, int nb, int* total)
{
    __shared__ int lds[256];
    __shared__ int carry;
    int t = threadIdx.x;
    if (t == 0) carry = 0;
    __syncthreads();
    for (int c0 = 0; c0 < nb; c0 += 256) {
        int i = c0 + t;
        int v = (i < nb) ? bsum[i] : 0;
        lds[t] = v;
        __syncthreads();
        for (int o = 1; o < 256; o <<= 1) {
            int add = (t >= o) ? lds[t - o] : 0;
            __syncthreads();
            lds[t] += add;
            __syncthreads();
        }
        int myc = carry;
        if (i < nb) bsum[i] = lds[t] - v + myc;
        int tot = lds[255];
        __syncthreads();
        if (t == 0) carry = myc + tot;
        __syncthreads();
    }
    if (total && t == 0) *total = carry;
}

__global__ void k_scan_pass3(const int* __restrict__ in, int n, const int* __restrict__ bsum,
                             int* __restrict__ out)
{
    __shared__ int lds[256];
    int b = blockIdx.x, t = threadIdx.x;
    int i0 = b * SCAN_CHUNK + t * 4;
    int v[4]; int s = 0;
    #pragma unroll
    for (int j = 0; j < 4; ++j) {
        int i = i0 + j;
        int x = 0;
        if (i < n) x = in[i];
        v[j] = x; s += x;
    }
    lds[t] = s;
    __syncthreads();
    for (int o = 1; o < 256; o <<= 1) {
        int add = (t >= o) ? lds[t - o] : 0;
        __syncthreads();
        lds[t] += add;
        __syncthreads();
    }
    int run = lds[t] - s + bsum[b];
    #pragma unroll
    for (int j = 0; j < 4; ++j) {
        int i = i0 + j;
        if (i < n) { out[i] = run; run += v[j]; }
    }
}

// ---------------------------------------------------------------- dual scan (value + predicate), for RGCN
__global__ void k_scan2_pass1(const int* __restrict__ in, int n, int* bV, int* bP)
{
    __shared__ int redV[256], redP[256];
    int b = blockIdx.x, t = threadIdx.x;
    int i0 = b * SCAN_CHUNK + t * 4;
    int sv = 0, sp = 0;
    #pragma unroll
    for (int j = 0; j < 4; ++j) {
        int i = i0 + j;
        if (i < n) { int v = in[i]; sv += v; sp += (v > 0); }
    }
    redV[t] = sv; redP[t] = sp;
    __syncthreads();
    for (int o = 128; o > 0; o >>= 1) {
        if (t < o) { redV[t] += redV[t + o]; redP[t] += redP[t + o]; }
        __syncthreads();
    }
    if (t == 0) { bV[b] = redV[0]; bP[b] = redP[0]; }
}

__global__ __launch_bounds__(256) void k_scan2_pass2(int* bV, int* bP, int nb, int* totalP)
{
    __shared__ int lds[256];
    __shared__ int carry;
    int t = threadIdx.x;
    #pragma unroll 1
    for (int which = 0; which < 2; ++which) {
        int* bsum = which ? bP : bV;
        __syncthreads();
        if (t == 0) carry = 0;
        __syncthreads();
        for (int c0 = 0; c0 < nb; c0 += 256) {
            int i = c0 + t;
            int v = (i < nb) ? bsum[i] : 0;
            lds[t] = v;
            __syncthreads();
            for (int o = 1; o < 256; o <<= 1) {
                int add = (t >= o) ? lds[t - o] : 0;
                __syncthreads();
                lds[t] += add;
                __syncthreads();
            }
            int myc = carry;
            if (i < nb) bsum[i] = lds[t] - v + myc;
            int tot = lds[255];
            __syncthreads();
            if (t == 0) carry = myc + tot;
            __syncthreads();
        }
        if (which == 1 && totalP && t == 0) *totalP = carry;
    }
}

__global__ void k_scan2_pass3(const int* __restrict__ in, int n,
                              const int* __restrict__ bV, const int* __restrict__ bP,
                              int* __restrict__ outV, int* __restrict__ outP)
{
    __shared__ int ldsV[256], ldsP[256];
    int b = blockIdx.x, t = threadIdx.x;
    int i0 = b * SCAN_CHUNK + t * 4;
    int v[4]; int sv = 0, sp = 0;
    #pragma unroll
    for (int j = 0; j < 4; ++j) {
        int i = i0 + j;
        int x = 0;
        if (i < n) x = in[i];
        v[j] = x; sv += x; sp += (x > 0);
    }
    ldsV[t] = sv; ldsP[t] = sp;
    __syncthreads();
    for (int o = 1; o < 256; o <<= 1) {
        int addV = (t >= o) ? ldsV[t - o] : 0;
        int addP = (t >= o) ? ldsP[t - o] : 0;
        __syncthreads();
        ldsV[t] += addV; ldsP[t] += addP;
        __syncthreads();
    }
    int runV = ldsV[t] - sv + bV[b];
    int runP = ldsP[t] - sp + bP[b];
    #pragma unroll
    for (int j = 0; j < 4; ++j) {
        int i = i0 + j;
        if (i < n) {
            outV[i] = runV; outP[i] = runP;
            runV += v[j]; runP += (v[j] > 0);
        }
    }
}

// ---------------------------------------------------------------- RGCN sort
__global__ void k_hist_rgcn(const int* __restrict__ dst, const int* __restrict__ et,
                            int* hist, int E)
{
    int i = blockIdx.x * blockDim.x + threadIdx.x;
    if (i < E) atomicAdd(&hist[(size_t)et[i] * DN + dst[i]], 1);
}

__global__ void k_seglist(const int* __restrict__ hist, const int* __restrict__ segpos,
                          int* __restrict__ seglist, int n)
{
    int i = blockIdx.x * blockDim.x + threadIdx.x;
    if (i < n && hist[i] > 0) seglist[segpos[i]] = i;
}

__global__ void k_stypebase(const int* __restrict__ segpos, int* stypebase)
{
    int t = threadIdx.x;
    if (t < DR) stypebase[t] = segpos[(size_t)t * DN];
}

__global__ void k_bucket_rgcn(const int* __restrict__ src, const int* __restrict__ dst,
                              const int* __restrict__ et, const int* __restrict__ off,
                              int* cur, int* ssrc, int E)
{
    int i = blockIdx.x * blockDim.x + threadIdx.x;
    if (i >= E) return;
    int key = et[i] * DN + dst[i];
    int pos = off[key] + atomicAdd(&cur[key], 1);
    ssrc[pos] = src[i];
}

// ---------------------------------------------------------------- hypergraph (both sides combined, 40000 bins)
__global__ void k_hist_p2(const int* __restrict__ se, const int* __restrict__ ke, int* hist)
{
    int i = blockIdx.x * blockDim.x + threadIdx.x;
    if (i < DP) atomicAdd(&hist[se[i]], 1);
    else if (i < 2 * DP) atomicAdd(&hist[DHE + ke[i - DP]], 1);
}

__global__ void k_bucket_p2(const int* __restrict__ sn, const int* __restrict__ se,
                            const int* __restrict__ kn, const int* __restrict__ ke,
                            const int* __restrict__ off, int* cur, int* pns)
{
    int i = blockIdx.x * blockDim.x + threadIdx.x;
    if (i >= 2 * DP) return;
    int e, node;
    if (i < DP) { e = se[i]; node = sn[i]; }
    else { e = DHE + ke[i - DP]; node = kn[i - DP]; }
    int pos = off[e] + atomicAdd(&cur[e], 1);
    pns[pos] = node;
}

// one wave per NEEDED hyperedge: efeat[he] = mean of kg[node]; half-wave float4 gather, 4 rows in flight
__global__ void k_hyper_agg(const float* __restrict__ xsrc, const int* __restrict__ pns,
                            const int* __restrict__ hoff, const int* __restrict__ hcnt,
                            const int* __restrict__ heneed, float* __restrict__ efeat)
{
    int lane = threadIdx.x & 63;
    int he = (blockIdx.x * blockDim.x + threadIdx.x) >> 6;
    if (he >= DHE2) return;
    if (!heneed[he]) return;
    int st = hoff[he], len = hcnt[he];
    int half = lane >> 5;
    int c16 = (lane & 31) * 4;
    float4 acc = make_float4(0.f, 0.f, 0.f, 0.f);
    int c = 0;
    for (; c + 4 <= len; c += 4) {
        int n0 = pns[st + c + half];
        int n1 = pns[st + c + 2 + half];
        float4 v0 = *(const float4*)&xsrc[(size_t)n0 * 128 + c16];
        float4 v1 = *(const float4*)&xsrc[(size_t)n1 * 128 + c16];
        acc.x += v0.x + v1.x; acc.y += v0.y + v1.y;
        acc.z += v0.z + v1.z; acc.w += v0.w + v1.w;
    }
    for (; c < len; c += 2) {
        int idx = c + half;
        if (idx < len) {
            int n = pns[st + idx];
            float4 v = *(const float4*)&xsrc[(size_t)n * 128 + c16];
            acc.x += v.x; acc.y += v.y; acc.z += v.z; acc.w += v.w;
        }
    }
    acc.x += __shfl_xor(acc.x, 32);
    acc.y += __shfl_xor(acc.y, 32);
    acc.z += __shfl_xor(acc.z, 32);
    acc.w += __shfl_xor(acc.w, 32);
    if (half == 0) {
        float inv = (len > 0) ? 1.0f / (float)len : 0.f;
        float4 o = make_float4(acc.x * inv, acc.y * inv, acc.z * inv, acc.w * inv);
        *(float4*)&efeat[(size_t)he * 128 + c16] = o;
    }
}

__global__ void k_slot_assign2(const int* __restrict__ sidx, const int* __restrict__ kidx,
                               int* slot_s, int* slot_k, int* scnt)
{
    int i = blockIdx.x * blockDim.x + threadIdx.x;
    if (i < DB * DLR) {
        int node = sidx[i];
        if (atomicCAS(&slot_s[node], -1, -2) == -1) slot_s[node] = atomicAdd(&scnt[0], 1);
    } else if (i < 2 * DB * DLR) {
        int node = kidx[i - DB * DLR];
        if (atomicCAS(&slot_k[node], -1, -2) == -1) slot_k[node] = atomicAdd(&scnt[1], 1);
    }
}

// fused sdeg + match + need-flag, block-aggregated compaction
__global__ __launch_bounds__(256) void k_sdeg_match(
    const int* __restrict__ nodes, const int* __restrict__ he, const int* __restrict__ slot,
    float* sdeg, int* mcnt, int* mhe, int* msl, int* heneed, int heBase)
{
    __shared__ int lcnt, lbase;
    if (threadIdx.x == 0) lcnt = 0;
    __syncthreads();
    int i = blockIdx.x * 256 + threadIdx.x;
    int s = -1, lidx = 0, h = 0;
    if (i < DP) {
        s = slot[nodes[i]];
        if (s >= 0) {
            h = heBase + he[i];
            heneed[h] = 1;
            atomicAdd(&sdeg[s], 1.0f);
            lidx = atomicAdd(&lcnt, 1);
        }
    }
    __syncthreads();
    if (threadIdx.x == 0) lbase = (lcnt > 0) ? atomicAdd(mcnt, lcnt) : 0;
    __syncthreads();
    if (s >= 0) {
        int idx = lbase + lidx;
        if (idx < MCAP) { mhe[idx] = h; msl[idx] = s; }
    }
}

// both sides in one launch
__global__ void k_accmatch2(const float* __restrict__ efeat,
                            const int* __restrict__ mhe_s, const int* __restrict__ msl_s,
                            const int* __restrict__ mhe_k, const int* __restrict__ msl_k,
                            const int* __restrict__ mcnt,
                            float* sacc_s, float* sacc_k)
{
    int lane = threadIdx.x & 63;
    int w = (blockIdx.x * blockDim.x + threadIdx.x) >> 6;
    int nw = (gridDim.x * blockDim.x) >> 6;
    int Ms = min(mcnt[0], MCAP), Mk = min(mcnt[1], MCAP);
    for (int i = w; i < Ms + Mk; i += nw) {
        bool sess = i < Ms;
        int he = sess ? mhe_s[i] : mhe_k[i - Ms];
        int sl = sess ? msl_s[i] : msl_k[i - Ms];
        float* sacc = sess ? sacc_s : sacc_k;
        float2 v = *(const float2*)&efeat[(size_t)he * 128 + lane * 2];
        atomicAdd(&sacc[(size_t)sl * 128 + lane * 2],     v.x);
        atomicAdd(&sacc[(size_t)sl * 128 + lane * 2 + 1], v.y);
    }
}

// both sides in one launch
__global__ void k_rel_gather2(const float* __restrict__ so_s, const float* __restrict__ so_k,
                              const int* __restrict__ slot_s, const int* __restrict__ slot_k,
                              const int* __restrict__ ridx_s, const int* __restrict__ ridx_k,
                              float* __restrict__ related)
{
    int gid = blockIdx.x * blockDim.x + threadIdx.x;
    int i = gid >> 5, c = gid & 31;
    if (i >= 2 * DB * DLR) return;
    bool sess = i < DB * DLR;
    int ii = sess ? i : i - DB * DLR;
    int s = sess ? slot_s[ridx_s[ii]] : slot_k[ridx_k[ii]];
    const float* so = sess ? so_s : so_k;
    int b = ii / DLR, l = ii % DLR;
    int colOff = sess ? 0 : 64;
    ((float4*)&related[((size_t)b * 128 + colOff + l) * 128])[c] =
        ((const float4*)&so[(size_t)s * 128])[c];
}

// ---------------------------------------------------------------- gathers / misc
__global__ void k_gather_rows(const float* __restrict__ src, const int* __restrict__ idx,
                              float* dst, int nRows)
{
    int i = blockIdx.x * blockDim.x + threadIdx.x;
    if (i >= nRows * 128) return;
    int row = i >> 7, d = i & 127;
    dst[i] = src[(size_t)idx[row] * 128 + d];
}

// ---------------------------------------------------------------- MHA: one block per (b,h)
__global__ __launch_bounds__(256) void k_mha(const float* __restrict__ qb,
                                             const float* __restrict__ kb,
                                             const float* __restrict__ vb,
                                             float* __restrict__ ob)
{
    int b = blockIdx.x >> 3, h = blockIdx.x & 7;
    __shared__ float Ks[128][16], Vs[128][16], Qs[32][16];
    int tid = threadIdx.x;
    for (int i = tid; i < 128 * 16; i += 256) {
        int j = i >> 4, d = i & 15;
        Ks[j][d] = kb[((size_t)b * 128 + j) * 128 + h * 16 + d];
        Vs[j][d] = vb[((size_t)b * 128 + j) * 128 + h * 16 + d];
    }
    for (int i = tid; i < 32 * 16; i += 256) {
        int q = i >> 4, d = i & 15;
        Qs[q][d] = qb[((size_t)b * 32 + q) * 128 + h * 16 + d] * 0.25f;
    }
    __syncthreads();
    int q = tid >> 3;
    int jg = tid & 7;
    float lg[16];
    float m = -1e30f;
    #pragma unroll
    for (int jj = 0; jj < 16; ++jj) {
        int j = jg * 16 + jj;
        float s = 0.f;
        #pragma unroll
        for (int d = 0; d < 16; ++d) s += Qs[q][d] * Ks[j][d];
        lg[jj] = s;
        m = fmaxf(m, s);
    }
    #pragma unroll
    for (int o = 1; o < 8; o <<= 1) m = fmaxf(m, __shfl_xor(m, o));
    float sum = 0.f;
    float acc[16] = {};
    #pragma unroll
    for (int jj = 0; jj < 16; ++jj) {
        float p = __expf(lg[jj] - m);
        sum += p;
        int j = jg * 16 + jj;
        #pragma unroll
        for (int d = 0; d < 16; ++d) acc[d] += p * Vs[j][d];
    }
    #pragma unroll
    for (int o = 1; o < 8; o <<= 1) {
        sum += __shfl_xor(sum, o);
        #pragma unroll
        for (int d = 0; d < 16; ++d) acc[d] += __shfl_xor(acc[d], o);
    }
    if (jg == 0) {
        float inv = 1.0f / sum;
        #pragma unroll
        for (int d = 0; d < 16; ++d)
            ob[((size_t)b * 32 + q) * 128 + h * 16 + d] = acc[d] * inv;
    }
}

// ---------------------------------------------------------------- launch
extern "C" void kernel_launch(void* const* d_in, const int* in_sizes, int n_in,
                              void* d_out, int out_size, void* d_ws, size_t ws_size,
                              hipStream_t stream)
{
    const float* emb        = (const float*)d_in[0];
    const float* bases      = (const float*)d_in[1];
    const float* comp       = (const float*)d_in[2];
    const float* root       = (const float*)d_in[3];
    const float* rgcn_bias  = (const float*)d_in[4];
    const float* sess_theta = (const float*)d_in[5];
    const float* sess_bias  = (const float*)d_in[6];
    const float* know_theta = (const float*)d_in[7];
    const float* know_bias  = (const float*)d_in[8];
    const float* in_proj_w  = (const float*)d_in[9];
    const float* in_proj_b  = (const float*)d_in[10];
    const float* out_proj_w = (const float*)d_in[11];
    const float* out_proj_b = (const float*)d_in[12];
    const float* attn_his_a = (const float*)d_in[13];
    const float* attn_his_b = (const float*)d_in[14];
    const float* attn_a     = (const float*)d_in[15];
    const float* attn_b     = (const float*)d_in[16];
    const float* rec_bias   = (const float*)d_in[17];
    const int* edge_src     = (const int*)d_in[18];
    const int* edge_dst     = (const int*)d_in[19];
    const int* edge_type    = (const int*)d_in[20];
    const int* sess_nodes   = (const int*)d_in[21];
    const int* sess_edges   = (const int*)d_in[22];
    const int* know_nodes   = (const int*)d_in[23];
    const int* know_edges   = (const int*)d_in[24];
    const int* sess_rel_idx = (const int*)d_in[25];
    const int* know_rel_idx = (const int*)d_in[26];
    const int* context_idx  = (const int*)d_in[27];
    float* out = (float*)d_out;

    float* wsf = (float*)d_ws;
    size_t off = 0;
    auto alloc = [&](size_t n) { size_t r = off; off += (n + 255) & ~(size_t)255; return r; };
    float* kg      = wsf + alloc(12800000);          // N*D
    float* tmp     = wsf + alloc(12800000);          // RGCN sort arena + efeat + split arenas tail
    ushortT* warena = (ushortT*)(wsf + alloc(196608)); // 12 x 64KB split w[r] (was fp32 w_all)
    int*   bsumV   = (int*)(wsf + alloc(2048));
    int*   bsumP   = (int*)(wsf + alloc(2048));
    int*   stybase = (int*)(wsf + alloc(16));
    // ---- contiguous zero block (one memset) ----
    size_t zstart = off;
    int*   hhist   = (int*)(wsf + alloc(DHE2));
    int*   hcur    = (int*)(wsf + alloc(DHE2));
    int*   heneed  = (int*)(wsf + alloc(DHE2));
    int*   mcnt    = (int*)(wsf + alloc(16));        // [0]=sess, [1]=know
    int*   scnt    = (int*)(wsf + alloc(16));
    float* sdeg_s  = wsf + alloc(4096);
    float* sdeg_k  = wsf + alloc(4096);
    float* sacc_s  = wsf + alloc(524288);
    float* sacc_k  = wsf + alloc(524288);
    size_t zend = off;
    // ---- contiguous 0xFF block (one memset) ----
    size_t fstart = off;
    int*   slot_s  = (int*)(wsf + alloc(100000));
    int*   slot_k  = (int*)(wsf + alloc(100000));
    size_t fend = off;
    int*   hoff    = (int*)(wsf + alloc(DHE2));
    int*   pns     = (int*)(wsf + alloc(2 * DP));
    int*   mhe_s   = (int*)(wsf + alloc(MCAP));
    int*   msl_s   = (int*)(wsf + alloc(MCAP));
    int*   mhe_k   = (int*)(wsf + alloc(MCAP));
    int*   msl_k   = (int*)(wsf + alloc(MCAP));
    float* so_s    = wsf + alloc(524288);
    float* so_k    = wsf + alloc(524288);
    float* related = wsf + alloc(1048576);
    float* ctx     = wsf + alloc(262144);
    float* qb      = wsf + alloc(262144);
    float* kb      = wsf + alloc(1048576);
    float* vb      = wsf + alloc(1048576);
    float* obuf    = wsf + alloc(262144);
    float* attrel  = wsf + alloc(262144);
    float* his     = wsf + alloc(8192);
    float* ucat    = wsf + alloc(270336);
    float* userb   = wsf + alloc(8192);
    float* e1      = wsf + alloc(2048);
    float* e2      = wsf + alloc(2112);
    (void)ws_size; (void)in_sizes; (void)n_in; (void)out_size;

    // RGCN sort arena inside tmp; efeat (40000*128 = 5.12M) in the tail;
    // split-weight arenas in the dead tail after efeat (tmp used: 12.12M of 12.8M floats)
    int*   hist    = (int*)tmp;                 // 1.2M
    int*   rcur    = (int*)tmp + 1200000;       // 1.2M (bucket cursor, pre-zeroed with hist)
    int*   soff    = (int*)tmp + 2400000;       // 1.2M
    int*   segpos  = (int*)tmp + 3600000;       // 1.2M
    int*   seglist = (int*)tmp + 4800000;       // 1.2M
    int*   ssrc    = (int*)tmp + 6000000;       // 1.0M
    float* efeat   = tmp + 7000000;             // 5.12M (used only after RGCN finishes)
    ushortT* wsplit = (ushortT*)(tmp + 12200000); // 9 x 32768 ushorts = 147456 floats
    ushortT* usplit = (ushortT*)(tmp + 12400000); // 16384 ushorts = 8192 floats

    const int nbR = (NRBINS + SCAN_CHUNK - 1) / SCAN_CHUNK;   // 1172
    const int nbH = (DHE2 + SCAN_CHUNK - 1) / SCAN_CHUNK;     // 40

    // ---------------- upfront memsets (3 total)
    hipMemsetAsync(wsf + zstart, 0, (zend - zstart) * 4, stream);
    hipMemsetAsync(wsf + fstart, 0xFF, (fend - fstart) * 4, stream);
    hipMemsetAsync(hist, 0, 2400000 * 4, stream);   // hist + rcur

    // weight pre-split (independent of everything else)
    k_presplit_all<<<576, 256, 0, stream>>>(root, sess_theta, know_theta, in_proj_w,
                                            out_proj_w, attn_his_a, attn_a, wsplit);

    k_slot_assign2<<<32, 256, 0, stream>>>(sess_rel_idx, know_rel_idx, slot_s, slot_k, scnt);
    // sdeg/match/need-flags early (only depend on slot arrays)
    k_sdeg_match<<<(DP + 255) / 256, 256, 0, stream>>>(sess_nodes, sess_edges, slot_s,
                                                       sdeg_s, mcnt, mhe_s, msl_s, heneed, 0);
    k_sdeg_match<<<(DP + 255) / 256, 256, 0, stream>>>(know_nodes, know_edges, slot_k,
                                                       sdeg_k, mcnt + 1, mhe_k, msl_k, heneed, DHE);

    // ---------------- RGCN: sort edges by (type, dst)
    k_hist_rgcn<<<(DE + 255) / 256, 256, 0, stream>>>(edge_dst, edge_type, hist, DE);
    k_scan2_pass1<<<nbR, 256, 0, stream>>>(hist, NRBINS, bsumV, bsumP);
    k_scan2_pass2<<<1, 256, 0, stream>>>(bsumV, bsumP, nbR, stybase + DR);
    k_scan2_pass3<<<nbR, 256, 0, stream>>>(hist, NRBINS, bsumV, bsumP, soff, segpos);
    k_stypebase<<<1, 64, 0, stream>>>(segpos, stybase);
    k_seglist<<<(NRBINS + 255) / 256, 256, 0, stream>>>(hist, segpos, seglist, NRBINS);
    k_bucket_rgcn<<<(DE + 255) / 256, 256, 0, stream>>>(edge_src, edge_dst, edge_type,
                                                        soff, rcur, ssrc, DE);
    k_wcomp_split<<<(DR * DD * DD + 255) / 256, 256, 0, stream>>>(comp, bases, warena);

    int gemmN = (DN + 63) / 64;
    k_gemm_ds<<<gemmN, 256, 0, stream>>>(emb, wsplit + 0 * 32768, rgcn_bias, nullptr, kg, DN);
    for (int r = 0; r < DR; ++r)
        k_rgcn_ds<<<gemmN, 256, 0, stream>>>(emb, warena, seglist, soff, hist, ssrc,
                                             stybase, kg, r);

    // ---------------- hypergraph (both sides as one 40000-edge problem)
    k_hist_p2<<<(2 * DP + 255) / 256, 256, 0, stream>>>(sess_edges, know_edges, hhist);
    k_scan_pass1<<<nbH, 256, 0, stream>>>(hhist, DHE2, bsumV);
    k_scan_pass2p<<<1, 256, 0, stream>>>(bsumV, nbH, nullptr);
    k_scan_pass3<<<nbH, 256, 0, stream>>>(hhist, DHE2, bsumV, hoff);
    k_bucket_p2<<<(2 * DP + 255) / 256, 256, 0, stream>>>(sess_nodes, sess_edges,
                                                          know_nodes, know_edges,
                                                          hoff, hcur, pns);
    k_hyper_agg<<<(DHE2 * 64 + 255) / 256, 256, 0, stream>>>(kg, pns, hoff, hhist, heneed, efeat);
    k_accmatch2<<<256, 256, 0, stream>>>(efeat, mhe_s, msl_s, mhe_k, msl_k, mcnt, sacc_s, sacc_k);

    k_gemm_ds<<<64, 256, 0, stream>>>(sacc_s, wsplit + 1 * 32768, sess_bias, sdeg_s, so_s, 4096);
    k_gemm_ds<<<64, 256, 0, stream>>>(sacc_k, wsplit + 2 * 32768, know_bias, sdeg_k, so_k, 4096);
    k_rel_gather2<<<(2 * DB * DLR * 32 + 255) / 256, 256, 0, stream>>>(
        so_s, so_k, slot_s, slot_k, sess_rel_idx, know_rel_idx, related);

    // ---------------- context + MHA
    k_gather_rows<<<(DB * DLC * 128 + 255) / 256, 256, 0, stream>>>(kg, context_idx, ctx, DB * DLC);
    k_gemm_ds<<<(DB * DLC + 63) / 64, 256, 0, stream>>>(ctx, wsplit + 3 * 32768,
                                                        in_proj_b, nullptr, qb, DB * DLC);
    k_gemm_ds<<<(DB * 128 + 63) / 64, 256, 0, stream>>>(related, wsplit + 4 * 32768,
                                                        in_proj_b + DD, nullptr, kb, DB * 128);
    k_gemm_ds<<<(DB * 128 + 63) / 64, 256, 0, stream>>>(related, wsplit + 5 * 32768,
                                                        in_proj_b + 2 * DD, nullptr, vb, DB * 128);
    k_mha<<<DB * DNH, 256, 0, stream>>>(qb, kb, vb, obuf);
    k_gemm_ds<<<(DB * DLC + 63) / 64, 256, 0, stream>>>(obuf, wsplit + 6 * 32768,
                                                        out_proj_b, nullptr, attrel, DB * DLC);

    // ---------------- pooling (GEMM-shaped) + score
    k_tanh_dot_ds<<<(DB * DLC + 63) / 64, 256, 0, stream>>>(attrel, wsplit + 7 * 32768,
                                                            attn_his_b, e1, DB * DLC);
    k_pool_apply<32><<<DB, 128, 0, stream>>>(attrel, e1, his);
    k_build_ucat<<<(DB * 33 * 128 + 255) / 256, 256, 0, stream>>>(ctx, his, ucat);
    k_tanh_dot_ds<<<(DB * 33 + 63) / 64, 256, 0, stream>>>(ucat, wsplit + 8 * 32768,
                                                           attn_b, e2, DB * 33);
    k_pool_apply<33><<<DB, 128, 0, stream>>>(ucat, e2, userb);
    k_presplit_user<<<32, 256, 0, stream>>>(userb, usplit);
    k_score_ds<<<gemmN, 256, 0, stream>>>(kg, usplit, rec_bias, out);
}

// Round 2
// 985.310 us; speedup vs baseline: 1.1112x; 1.1112x over previous
//
#include <hip/hip_runtime.h>
#include <hip/hip_bf16.h>

#define DN 100000     // N entities
#define DD 128        // D
#define DR 12         // R relations
#define DNB 8         // bases
#define DE 1000000    // edges
#define DP 400000     // hyperedge incidences
#define DHE 20000     // hyperedges
#define DHE2 40000    // both sides combined
#define DB 64         // batch
#define DLR 64
#define DLC 32
#define DNH 8
#define DHD 16
#define NRBINS (DR * DN)   // 1.2M
#define SCAN_CHUNK 1024
#define MCAP 65536

typedef unsigned short ushortT;
typedef unsigned int uintT;
typedef __attribute__((ext_vector_type(8))) short s8v;
typedef __attribute__((ext_vector_type(4))) float f4v;

#define APAD 136   // 64 rows of K=128 bf16, stride 272B

__device__ __forceinline__ ushortT rneb(float v) {
    uintT b = __float_as_uint(v);
    return (ushortT)((b + 0x7FFFu + ((b >> 16) & 1u)) >> 16);
}
__device__ __forceinline__ float b2f(ushortT h) {
    return __uint_as_float(((uintT)h) << 16);
}

__device__ __forceinline__ void split_store8(ushortT* hbase, ushortT* lbase, const float* v)
{
    ushortT h[8], l[8];
    #pragma unroll
    for (int j = 0; j < 8; ++j) {
        h[j] = rneb(v[j]);
        l[j] = rneb(v[j] - b2f(h[j]));
    }
    uint4 hv = make_uint4((uintT)h[0] | ((uintT)h[1] << 16), (uintT)h[2] | ((uintT)h[3] << 16),
                          (uintT)h[4] | ((uintT)h[5] << 16), (uintT)h[6] | ((uintT)h[7] << 16));
    uint4 lv = make_uint4((uintT)l[0] | ((uintT)l[1] << 16), (uintT)l[2] | ((uintT)l[3] << 16),
                          (uintT)l[4] | ((uintT)l[5] << 16), (uintT)l[6] | ((uintT)l[7] << 16));
    *(uint4*)hbase = hv;
    *(uint4*)lbase = lv;
}

// ---------------------------------------------------------------- weight pre-split (blocked fragment layout)
// WB[kc][n][k] (k in [0,32), n in [0,N)) ushort, h plane then l plane at +4*N*32.
// element value = trans ? W[n*128 + kc*32+k] : W[(kc*32+k)*128 + n]

// 9 static 128x128 matrices in one launch:
// 0 root(t0) 1 sess_theta(t0) 2 know_theta(t0) 3 wq(t1) 4 wk(t1) 5 wv(t1)
// 6 out_proj(t1) 7 attn_his_a(t0) 8 attn_a(t0)
__global__ __launch_bounds__(256) void k_presplit_all(
    const float* __restrict__ root, const float* __restrict__ st,
    const float* __restrict__ kt, const float* __restrict__ ipw,
    const float* __restrict__ opw, const float* __restrict__ aha,
    const float* __restrict__ aa, ushortT* __restrict__ outA)
{
    int gid = blockIdx.x * 256 + threadIdx.x;   // 9*16384 exact
    int mat = gid >> 14, e = gid & 16383;
    const float* srcs[9] = {root, st, kt, ipw, ipw + 16384, ipw + 32768, opw, aha, aa};
    const float* W = srcs[mat];
    bool t1 = (mat >= 3 && mat <= 6);
    int k = e & 31, n = (e >> 5) & 127, kc = e >> 12;
    float f = t1 ? W[(size_t)n * 128 + kc * 32 + k] : W[(size_t)(kc * 32 + k) * 128 + n];
    ushortT h = rneb(f);
    outA[(size_t)mat * 32768 + e] = h;
    outA[(size_t)mat * 32768 + 16384 + e] = rneb(f - b2f(h));
}

// w[r] = comp[r]·bases, split directly into blocked layout (64KB per r: h 32KB, l 32KB)
__global__ void k_wcomp_split(const float* __restrict__ comp, const float* __restrict__ bases,
                              ushortT* __restrict__ warena)
{
    int i = blockIdx.x * blockDim.x + threadIdx.x;
    if (i >= DR * DD * DD) return;
    int r = i / (DD * DD), io = i % (DD * DD);
    float s = 0.f;
    #pragma unroll
    for (int b = 0; b < DNB; ++b) s += comp[r * DNB + b] * bases[(size_t)b * DD * DD + io];
    int irow = io >> 7, o = io & 127;          // w[r][irow][o], irow = k-dim
    int kc = irow >> 5, k = irow & 31;
    size_t dst = (size_t)r * 32768 + (size_t)kc * 4096 + o * 32 + k;
    ushortT h = rneb(s);
    warena[dst] = h;
    warena[dst + 16384] = rneb(s - b2f(h));
}

// ---------------------------------------------------------------- MFMA GEMM, B copy-staged per kc from pre-split global
__global__ __launch_bounds__(256) void k_gemm_ds(
    const float* __restrict__ A, const ushortT* __restrict__ Wb,
    const float* __restrict__ bias, const float* __restrict__ rs,
    float* __restrict__ C, int M)
{
    __shared__ __align__(16) ushortT Ah[64 * APAD], Al[64 * APAD];
    __shared__ __align__(16) ushortT Bs[8192];   // h [0,4096), l [4096,8192) for current kc
    int tid = threadIdx.x;
    int row0 = blockIdx.x * 64;
    {
        int row = tid >> 2, c0 = (tid & 3) * 32;
        int gr = row0 + row;
        const float* ar = A + (size_t)gr * 128 + c0;
        float sc = 1.0f;
        if (rs && gr < M) { float d = rs[gr]; sc = (d > 0.f) ? 1.0f / d : 0.f; }
        #pragma unroll
        for (int g = 0; g < 4; ++g) {
            float v[8] = {};
            if (gr < M) {
                float4 u0 = *(const float4*)(ar + g * 8);
                float4 u1 = *(const float4*)(ar + g * 8 + 4);
                v[0]=u0.x*sc; v[1]=u0.y*sc; v[2]=u0.z*sc; v[3]=u0.w*sc;
                v[4]=u1.x*sc; v[5]=u1.y*sc; v[6]=u1.z*sc; v[7]=u1.w*sc;
            }
            split_store8(&Ah[row * APAD + c0 + g * 8], &Al[row * APAD + c0 + g * 8], v);
        }
    }
    f4v acc[8] = {};
    int w = tid >> 6, lane = tid & 63, m = lane & 15, quad = lane >> 4;
    for (int kc = 0; kc < 4; ++kc) {
        __syncthreads();
        {   // pure-copy stage of B kc-slab: 8KB h + 8KB l
            const ushortT* gh = Wb + kc * 4096;
            const ushortT* gl = Wb + 16384 + kc * 4096;
            *(s8v*)&Bs[tid * 8]        = *(const s8v*)&gh[tid * 8];
            *(s8v*)&Bs[2048 + tid * 8] = *(const s8v*)&gh[2048 + tid * 8];
            *(s8v*)&Bs[4096 + tid * 8] = *(const s8v*)&gl[tid * 8];
            *(s8v*)&Bs[6144 + tid * 8] = *(const s8v*)&gl[2048 + tid * 8];
        }
        __syncthreads();
        s8v ah = *(const s8v*)&Ah[(w * 16 + m) * APAD + kc * 32 + quad * 8];
        s8v al = *(const s8v*)&Al[(w * 16 + m) * APAD + kc * 32 + quad * 8];
        #pragma unroll
        for (int nt = 0; nt < 8; ++nt) {
            int boff = (nt * 16 + m) * 32 + quad * 8;
            s8v bh = *(const s8v*)&Bs[boff];
            s8v bl = *(const s8v*)&Bs[4096 + boff];
            acc[nt] = __builtin_amdgcn_mfma_f32_16x16x32_bf16(ah, bh, acc[nt], 0, 0, 0);
            acc[nt] = __builtin_amdgcn_mfma_f32_16x16x32_bf16(al, bh, acc[nt], 0, 0, 0);
            acc[nt] = __builtin_amdgcn_mfma_f32_16x16x32_bf16(ah, bl, acc[nt], 0, 0, 0);
        }
    }
    float bv[8];
    #pragma unroll
    for (int nt = 0; nt < 8; ++nt) bv[nt] = bias ? bias[nt * 16 + m] : 0.f;
    #pragma unroll
    for (int rr = 0; rr < 4; ++rr) {
        int gr = row0 + w * 16 + quad * 4 + rr;
        if (gr < M) {
            #pragma unroll
            for (int nt = 0; nt < 8; ++nt)
                C[(size_t)gr * 128 + nt * 16 + m] = acc[nt][rr] + bv[nt];
        }
    }
}

// ---------------------------------------------------------------- fused e[row] = tanh(A@W)[row,:] . bvec
__global__ __launch_bounds__(256) void k_tanh_dot_ds(
    const float* __restrict__ A, const ushortT* __restrict__ Wb,
    const float* __restrict__ bvec, float* __restrict__ e, int M)
{
    __shared__ __align__(16) ushortT Ah[64 * APAD], Al[64 * APAD];
    __shared__ __align__(16) ushortT Bs[8192];
    int tid = threadIdx.x;
    int row0 = blockIdx.x * 64;
    {
        int row = tid >> 2, c0 = (tid & 3) * 32;
        int gr = row0 + row;
        const float* ar = A + (size_t)gr * 128 + c0;
        #pragma unroll
        for (int g = 0; g < 4; ++g) {
            float v[8] = {};
            if (gr < M) {
                float4 u0 = *(const float4*)(ar + g * 8);
                float4 u1 = *(const float4*)(ar + g * 8 + 4);
                v[0]=u0.x; v[1]=u0.y; v[2]=u0.z; v[3]=u0.w;
                v[4]=u1.x; v[5]=u1.y; v[6]=u1.z; v[7]=u1.w;
            }
            split_store8(&Ah[row * APAD + c0 + g * 8], &Al[row * APAD + c0 + g * 8], v);
        }
    }
    f4v acc[8] = {};
    int w = tid >> 6, lane = tid & 63, m = lane & 15, quad = lane >> 4;
    for (int kc = 0; kc < 4; ++kc) {
        __syncthreads();
        {
            const ushortT* gh = Wb + kc * 4096;
            const ushortT* gl = Wb + 16384 + kc * 4096;
            *(s8v*)&Bs[tid * 8]        = *(const s8v*)&gh[tid * 8];
            *(s8v*)&Bs[2048 + tid * 8] = *(const s8v*)&gh[2048 + tid * 8];
            *(s8v*)&Bs[4096 + tid * 8] = *(const s8v*)&gl[tid * 8];
            *(s8v*)&Bs[6144 + tid * 8] = *(const s8v*)&gl[2048 + tid * 8];
        }
        __syncthreads();
        s8v ah = *(const s8v*)&Ah[(w * 16 + m) * APAD + kc * 32 + quad * 8];
        s8v al = *(const s8v*)&Al[(w * 16 + m) * APAD + kc * 32 + quad * 8];
        #pragma unroll
        for (int nt = 0; nt < 8; ++nt) {
            int boff = (nt * 16 + m) * 32 + quad * 8;
            s8v bh = *(const s8v*)&Bs[boff];
            s8v bl = *(const s8v*)&Bs[4096 + boff];
            acc[nt] = __builtin_amdgcn_mfma_f32_16x16x32_bf16(ah, bh, acc[nt], 0, 0, 0);
            acc[nt] = __builtin_amdgcn_mfma_f32_16x16x32_bf16(al, bh, acc[nt], 0, 0, 0);
            acc[nt] = __builtin_amdgcn_mfma_f32_16x16x32_bf16(ah, bl, acc[nt], 0, 0, 0);
        }
    }
    float bv[8];
    #pragma unroll
    for (int nt = 0; nt < 8; ++nt) bv[nt] = bvec[nt * 16 + m];
    #pragma unroll
    for (int rr = 0; rr < 4; ++rr) {
        float p = 0.f;
        #pragma unroll
        for (int nt = 0; nt < 8; ++nt) p += tanhf(acc[nt][rr]) * bv[nt];
        #pragma unroll
        for (int o = 1; o < 16; o <<= 1) p += __shfl_xor(p, o);
        int gr = row0 + w * 16 + quad * 4 + rr;
        if (m == 0 && gr < M) e[gr] = p;
    }
}

// ---------------------------------------------------------------- softmax(e) weighted sum of h rows (+ optional user split)
template <int L>
__global__ __launch_bounds__(128) void k_pool_apply(const float* __restrict__ h,
                                                    const float* __restrict__ e,
                                                    float* __restrict__ out,
                                                    ushortT* __restrict__ us)
{
    __shared__ float es[L];
    int b = blockIdx.x, tid = threadIdx.x;
    if (tid < L) es[tid] = e[b * L + tid];
    __syncthreads();
    float mx = -1e30f;
    #pragma unroll
    for (int l = 0; l < L; ++l) mx = fmaxf(mx, es[l]);
    float wgt[L];
    float sum = 0.f;
    #pragma unroll
    for (int l = 0; l < L; ++l) { wgt[l] = __expf(es[l] - mx); sum += wgt[l]; }
    float inv = 1.0f / sum;
    float o = 0.f;
    #pragma unroll
    for (int l = 0; l < L; ++l) o += wgt[l] * h[((size_t)b * L + l) * 128 + tid];
    float val = o * inv;
    out[(size_t)b * 128 + tid] = val;
    if (us) {   // split directly into blocked [kc][64][32] layout, l plane at +8192
        ushortT hh = rneb(val);
        ushortT ll = rneb(val - b2f(hh));
        int e_ = ((tid >> 5) * 2048) + b * 32 + (tid & 31);
        us[e_] = hh;
        us[8192 + e_] = ll;
    }
}

__global__ void k_build_ucat(const float* __restrict__ ctx, const float* __restrict__ his,
                             float* ucat)
{
    int i = blockIdx.x * blockDim.x + threadIdx.x;
    if (i >= DB * 33 * 128) return;
    int d = i & 127, l = (i >> 7) % 33, b = i / (33 * 128);
    ucat[i] = (l < 32) ? ctx[((size_t)b * 32 + l) * 128 + d] : his[(size_t)b * 128 + d];
}

// ---------------------------------------------------------------- RGCN fused segment-mean @ w[r] -> kg += (MFMA, B copy-staged)
__global__ __launch_bounds__(256) void k_rgcn_ds(
    const float* __restrict__ x, const ushortT* __restrict__ warena,
    const int* __restrict__ seglist, const int* __restrict__ soff,
    const int* __restrict__ slen, const int* __restrict__ ssrc,
    const int* __restrict__ stypebase, float* __restrict__ kg, int r)
{
    __shared__ __align__(16) ushortT Ah[64 * APAD], Al[64 * APAD];
    __shared__ __align__(16) ushortT Bs[8192];
    int s0 = stypebase[r], s1 = stypebase[r + 1];
    int base = s0 + blockIdx.x * 64;
    if (base >= s1) return;
    int nrow = min(64, s1 - base);
    int tid = threadIdx.x;
    const ushortT* Wb = warena + (size_t)r * 32768;
    {
        int row = tid >> 2, c0 = (tid & 3) * 32;
        float a[32] = {};
        if (row < nrow) {
            int key = seglist[base + row];
            int st = soff[key], len = slen[key];
            for (int i = 0; i < len; ++i) {
                const float* xr = x + (size_t)ssrc[st + i] * 128 + c0;
                #pragma unroll
                for (int j = 0; j < 8; ++j) {
                    float4 v = *(const float4*)(xr + j * 4);
                    a[j*4+0] += v.x; a[j*4+1] += v.y; a[j*4+2] += v.z; a[j*4+3] += v.w;
                }
            }
            float inv = 1.0f / (float)max(len, 1);
            #pragma unroll
            for (int j = 0; j < 32; ++j) a[j] *= inv;
        }
        #pragma unroll
        for (int g = 0; g < 4; ++g)
            split_store8(&Ah[row * APAD + c0 + g * 8], &Al[row * APAD + c0 + g * 8], a + g * 8);
    }
    f4v acc[8] = {};
    int w = tid >> 6, lane = tid & 63, m = lane & 15, quad = lane >> 4;
    for (int kc = 0; kc < 4; ++kc) {
        __syncthreads();
        {
            const ushortT* gh = Wb + kc * 4096;
            const ushortT* gl = Wb + 16384 + kc * 4096;
            *(s8v*)&Bs[tid * 8]        = *(const s8v*)&gh[tid * 8];
            *(s8v*)&Bs[2048 + tid * 8] = *(const s8v*)&gh[2048 + tid * 8];
            *(s8v*)&Bs[4096 + tid * 8] = *(const s8v*)&gl[tid * 8];
            *(s8v*)&Bs[6144 + tid * 8] = *(const s8v*)&gl[2048 + tid * 8];
        }
        __syncthreads();
        s8v ah = *(const s8v*)&Ah[(w * 16 + m) * APAD + kc * 32 + quad * 8];
        s8v al = *(const s8v*)&Al[(w * 16 + m) * APAD + kc * 32 + quad * 8];
        #pragma unroll
        for (int nt = 0; nt < 8; ++nt) {
            int boff = (nt * 16 + m) * 32 + quad * 8;
            s8v bh = *(const s8v*)&Bs[boff];
            s8v bl = *(const s8v*)&Bs[4096 + boff];
            acc[nt] = __builtin_amdgcn_mfma_f32_16x16x32_bf16(ah, bh, acc[nt], 0, 0, 0);
            acc[nt] = __builtin_amdgcn_mfma_f32_16x16x32_bf16(al, bh, acc[nt], 0, 0, 0);
            acc[nt] = __builtin_amdgcn_mfma_f32_16x16x32_bf16(ah, bl, acc[nt], 0, 0, 0);
        }
    }
    #pragma unroll
    for (int rr = 0; rr < 4; ++rr) {
        int rt = w * 16 + quad * 4 + rr;
        if (rt < nrow) {
            int dst = seglist[base + rt] - r * DN;
            float* kr = kg + (size_t)dst * 128 + m;
            #pragma unroll
            for (int nt = 0; nt < 8; ++nt)
                kr[nt * 16] += acc[nt][rr];
        }
    }
}

// ---------------------------------------------------------------- scoring (MFMA, B copy-staged from pre-split user)
__global__ __launch_bounds__(256) void k_score_ds(
    const float* __restrict__ kg, const ushortT* __restrict__ Ub,
    const float* __restrict__ rb, float* __restrict__ out)
{
    __shared__ __align__(16) ushortT Ah[64 * APAD], Al[64 * APAD];
    __shared__ __align__(16) ushortT Bs[4096];   // h [0,2048), l [2048,4096) for current kc
    int tid = threadIdx.x;
    int n0 = blockIdx.x * 64;
    {
        int row = tid >> 2, c0 = (tid & 3) * 32;
        int gr = n0 + row;
        const float* ar = kg + (size_t)gr * 128 + c0;
        #pragma unroll
        for (int g = 0; g < 4; ++g) {
            float v[8] = {};
            if (gr < DN) {
                float4 u0 = *(const float4*)(ar + g * 8);
                float4 u1 = *(const float4*)(ar + g * 8 + 4);
                v[0]=u0.x; v[1]=u0.y; v[2]=u0.z; v[3]=u0.w;
                v[4]=u1.x; v[5]=u1.y; v[6]=u1.z; v[7]=u1.w;
            }
            split_store8(&Ah[row * APAD + c0 + g * 8], &Al[row * APAD + c0 + g * 8], v);
        }
    }
    f4v acc[4] = {};
    int w = tid >> 6, lane = tid & 63, m = lane & 15, quad = lane >> 4;
    for (int kc = 0; kc < 4; ++kc) {
        __syncthreads();
        {
            const ushortT* gh = Ub + kc * 2048;
            const ushortT* gl = Ub + 8192 + kc * 2048;
            *(s8v*)&Bs[tid * 8]        = *(const s8v*)&gh[tid * 8];
            *(s8v*)&Bs[2048 + tid * 8] = *(const s8v*)&gl[tid * 8];
        }
        __syncthreads();
        s8v ah = *(const s8v*)&Ah[(w * 16 + m) * APAD + kc * 32 + quad * 8];
        s8v al = *(const s8v*)&Al[(w * 16 + m) * APAD + kc * 32 + quad * 8];
        #pragma unroll
        for (int nt = 0; nt < 4; ++nt) {
            int boff = (nt * 16 + m) * 32 + quad * 8;
            s8v bh = *(const s8v*)&Bs[boff];
            s8v bl = *(const s8v*)&Bs[2048 + boff];
            acc[nt] = __builtin_amdgcn_mfma_f32_16x16x32_bf16(ah, bh, acc[nt], 0, 0, 0);
            acc[nt] = __builtin_amdgcn_mfma_f32_16x16x32_bf16(al, bh, acc[nt], 0, 0, 0);
            acc[nt] = __builtin_amdgcn_mfma_f32_16x16x32_bf16(ah, bl, acc[nt], 0, 0, 0);
        }
    }
    int n = n0 + w * 16 + quad * 4;
    if (n < DN) {
        float4 rbv = *(const float4*)&rb[n];
        #pragma unroll
        for (int nt = 0; nt < 4; ++nt) {
            int b = nt * 16 + m;
            float4 o = make_float4(acc[nt][0] + rbv.x, acc[nt][1] + rbv.y,
                                   acc[nt][2] + rbv.z, acc[nt][3] + rbv.w);
            *(float4*)&out[(size_t)b * DN + n] = o;
        }
    }
}

// ---------------------------------------------------------------- scans (single-mode, for hyper)
__global__ void k_scan_pass1(const int* __restrict__ in, int n, int* __restrict__ bsum)
{
    __shared__ int red[256];
    int b = blockIdx.x, t = threadIdx.x;
    int i0 = b * SCAN_CHUNK + t * 4;
    int s = 0;
    #pragma unroll
    for (int j = 0; j < 4; ++j) {
        int i = i0 + j;
        if (i < n) s += in[i];
    }
    red[t] = s;
    __syncthreads();
    for (int o = 128; o > 0; o >>= 1) {
        if (t < o) red[t] += red[t + o];
        __syncthreads();
    }
    if (t == 0) bsum[b] = red[0];
}

__global__ __launch_bounds__(256) void k_scan_pass2p(int* bsum, int nb, int* total)
{
    __shared__ int lds[256];
    __shared__ int carry;
    int t = threadIdx.x;
    if (t == 0) carry = 0;
    __syncthreads();
    for (int c0 = 0; c0 < nb; c0 += 256) {
        int i = c0 + t;
        int v = (i < nb) ? bsum[i] : 0;
        lds[t] = v;
        __syncthreads();
        for (int o = 1; o < 256; o <<= 1) {
            int add = (t >= o) ? lds[t - o] : 0;
            __syncthreads();
            lds[t] += add;
            __syncthreads();
        }
        int myc = carry;
        if (i < nb) bsum[i] = lds[t] - v + myc;
        int tot = lds[255];
        __syncthreads();
        if (t == 0) carry = myc + tot;
        __syncthreads();
    }
    if (total && t == 0) *total = carry;
}

__global__ void k_scan_pass3(const int* __restrict__ in, int n, const int* __restrict__ bsum,
                             int* __restrict__ out)
{
    __shared__ int lds[256];
    int b = blockIdx.x, t = threadIdx.x;
    int i0 = b * SCAN_CHUNK + t * 4;
    int v[4]; int s = 0;
    #pragma unroll
    for (int j = 0; j < 4; ++j) {
        int i = i0 + j;
        int x = 0;
        if (i < n) x = in[i];
        v[j] = x; s += x;
    }
    lds[t] = s;
    __syncthreads();
    for (int o = 1; o < 256; o <<= 1) {
        int add = (t >= o) ? lds[t - o] : 0;
        __syncthreads();
        lds[t] += add;
        __syncthreads();
    }
    int run = lds[t] - s + bsum[b];
    #pragma unroll
    for (int j = 0; j < 4; ++j) {
        int i = i0 + j;
        if (i < n) { out[i] = run; run += v[j]; }
    }
}

// ---------------------------------------------------------------- dual scan (value + predicate), for RGCN
__global__ void k_scan2_pass1(const int* __restrict__ in, int n, int* bV, int* bP)
{
    __shared__ int redV[256], redP[256];
    int b = blockIdx.x, t = threadIdx.x;
    int i0 = b * SCAN_CHUNK + t * 4;
    int sv = 0, sp = 0;
    #pragma unroll
    for (int j = 0; j < 4; ++j) {
        int i = i0 + j;
        if (i < n) { int v = in[i]; sv += v; sp += (v > 0); }
    }
    redV[t] = sv; redP[t] = sp;
    __syncthreads();
    for (int o = 128; o > 0; o >>= 1) {
        if (t < o) { redV[t] += redV[t + o]; redP[t] += redP[t + o]; }
        __syncthreads();
    }
    if (t == 0) { bV[b] = redV[0]; bP[b] = redP[0]; }
}

__global__ __launch_bounds__(256) void k_scan2_pass2(int* bV, int* bP, int nb, int* totalP)
{
    __shared__ int lds[256];
    __shared__ int carry;
    int t = threadIdx.x;
    #pragma unroll 1
    for (int which = 0; which < 2; ++which) {
        int* bsum = which ? bP : bV;
        __syncthreads();
        if (t == 0) carry = 0;
        __syncthreads();
        for (int c0 = 0; c0 < nb; c0 += 256) {
            int i = c0 + t;
            int v = (i < nb) ? bsum[i] : 0;
            lds[t] = v;
            __syncthreads();
            for (int o = 1; o < 256; o <<= 1) {
                int add = (t >= o) ? lds[t - o] : 0;
                __syncthreads();
                lds[t] += add;
                __syncthreads();
            }
            int myc = carry;
            if (i < nb) bsum[i] = lds[t] - v + myc;
            int tot = lds[255];
            __syncthreads();
            if (t == 0) carry = myc + tot;
            __syncthreads();
        }
        if (which == 1 && totalP && t == 0) *totalP = carry;
    }
}

__global__ void k_scan2_pass3(const int* __restrict__ in, int n,
                              const int* __restrict__ bV, const int* __restrict__ bP,
                              int* __restrict__ outV, int* __restrict__ outP)
{
    __shared__ int ldsV[256], ldsP[256];
    int b = blockIdx.x, t = threadIdx.x;
    int i0 = b * SCAN_CHUNK + t * 4;
    int v[4]; int sv = 0, sp = 0;
    #pragma unroll
    for (int j = 0; j < 4; ++j) {
        int i = i0 + j;
        int x = 0;
        if (i < n) x = in[i];
        v[j] = x; sv += x; sp += (x > 0);
    }
    ldsV[t] = sv; ldsP[t] = sp;
    __syncthreads();
    for (int o = 1; o < 256; o <<= 1) {
        int addV = (t >= o) ? ldsV[t - o] : 0;
        int addP = (t >= o) ? ldsP[t - o] : 0;
        __syncthreads();
        ldsV[t] += addV; ldsP[t] += addP;
        __syncthreads();
    }
    int runV = ldsV[t] - sv + bV[b];
    int runP = ldsP[t] - sp + bP[b];
    #pragma unroll
    for (int j = 0; j < 4; ++j) {
        int i = i0 + j;
        if (i < n) {
            outV[i] = runV; outP[i] = runP;
            runV += v[j]; runP += (v[j] > 0);
        }
    }
}

// ---------------------------------------------------------------- RGCN sort
__global__ void k_hist_rgcn(const int* __restrict__ dst, const int* __restrict__ et,
                            int* hist, int E)
{
    int i = blockIdx.x * blockDim.x + threadIdx.x;
    if (i < E) atomicAdd(&hist[(size_t)et[i] * DN + dst[i]], 1);
}

__global__ void k_seglist(const int* __restrict__ hist, const int* __restrict__ segpos,
                          int* __restrict__ seglist, int n)
{
    int i = blockIdx.x * blockDim.x + threadIdx.x;
    if (i < n && hist[i] > 0) seglist[segpos[i]] = i;
}

__global__ void k_stypebase(const int* __restrict__ segpos, int* stypebase)
{
    int t = threadIdx.x;
    if (t < DR) stypebase[t] = segpos[(size_t)t * DN];
}

__global__ void k_bucket_rgcn(const int* __restrict__ src, const int* __restrict__ dst,
                              const int* __restrict__ et, const int* __restrict__ off,
                              int* cur, int* ssrc, int E)
{
    int i = blockIdx.x * blockDim.x + threadIdx.x;
    if (i >= E) return;
    int key = et[i] * DN + dst[i];
    int pos = off[key] + atomicAdd(&cur[key], 1);
    ssrc[pos] = src[i];
}

// ---------------------------------------------------------------- hypergraph (both sides combined, 40000 bins)
__global__ void k_hist_p2(const int* __restrict__ se, const int* __restrict__ ke, int* hist)
{
    int i = blockIdx.x * blockDim.x + threadIdx.x;
    if (i < DP) atomicAdd(&hist[se[i]], 1);
    else if (i < 2 * DP) atomicAdd(&hist[DHE + ke[i - DP]], 1);
}

__global__ void k_bucket_p2(const int* __restrict__ sn, const int* __restrict__ se,
                            const int* __restrict__ kn, const int* __restrict__ ke,
                            const int* __restrict__ off, int* cur, int* pns)
{
    int i = blockIdx.x * blockDim.x + threadIdx.x;
    if (i >= 2 * DP) return;
    int e, node;
    if (i < DP) { e = se[i]; node = sn[i]; }
    else { e = DHE + ke[i - DP]; node = kn[i - DP]; }
    int pos = off[e] + atomicAdd(&cur[e], 1);
    pns[pos] = node;
}

// one wave per NEEDED hyperedge: efeat[he] = mean of kg[node]; half-wave float4 gather, 4 rows in flight
__global__ void k_hyper_agg(const float* __restrict__ xsrc, const int* __restrict__ pns,
                            const int* __restrict__ hoff, const int* __restrict__ hcnt,
                            const int* __restrict__ heneed, float* __restrict__ efeat)
{
    int lane = threadIdx.x & 63;
    int he = (blockIdx.x * blockDim.x + threadIdx.x) >> 6;
    if (he >= DHE2) return;
    if (!heneed[he]) return;
    int st = hoff[he], len = hcnt[he];
    int half = lane >> 5;
    int c16 = (lane & 31) * 4;
    float4 acc = make_float4(0.f, 0.f, 0.f, 0.f);
    int c = 0;
    for (; c + 4 <= len; c += 4) {
        int n0 = pns[st + c + half];
        int n1 = pns[st + c + 2 + half];
        float4 v0 = *(const float4*)&xsrc[(size_t)n0 * 128 + c16];
        float4 v1 = *(const float4*)&xsrc[(size_t)n1 * 128 + c16];
        acc.x += v0.x + v1.x; acc.y += v0.y + v1.y;
        acc.z += v0.z + v1.z; acc.w += v0.w + v1.w;
    }
    for (; c < len; c += 2) {
        int idx = c + half;
        if (idx < len) {
            int n = pns[st + idx];
            float4 v = *(const float4*)&xsrc[(size_t)n * 128 + c16];
            acc.x += v.x; acc.y += v.y; acc.z += v.z; acc.w += v.w;
        }
    }
    acc.x += __shfl_xor(acc.x, 32);
    acc.y += __shfl_xor(acc.y, 32);
    acc.z += __shfl_xor(acc.z, 32);
    acc.w += __shfl_xor(acc.w, 32);
    if (half == 0) {
        float inv = (len > 0) ? 1.0f / (float)len : 0.f;
        float4 o = make_float4(acc.x * inv, acc.y * inv, acc.z * inv, acc.w * inv);
        *(float4*)&efeat[(size_t)he * 128 + c16] = o;
    }
}

__global__ void k_slot_assign2(const int* __restrict__ sidx, const int* __restrict__ kidx,
                               int* slot_s, int* slot_k, int* scnt)
{
    int i = blockIdx.x * blockDim.x + threadIdx.x;
    if (i < DB * DLR) {
        int node = sidx[i];
        if (atomicCAS(&slot_s[node], -1, -2) == -1) slot_s[node] = atomicAdd(&scnt[0], 1);
    } else if (i < 2 * DB * DLR) {
        int node = kidx[i - DB * DLR];
        if (atomicCAS(&slot_k[node], -1, -2) == -1) slot_k[node] = atomicAdd(&scnt[1], 1);
    }
}

// fused sdeg + match + need-flag, block-aggregated compaction
__global__ __launch_bounds__(256) void k_sdeg_match(
    const int* __restrict__ nodes, const int* __restrict__ he, const int* __restrict__ slot,
    float* sdeg, int* mcnt, int* mhe, int* msl, int* heneed, int heBase)
{
    __shared__ int lcnt, lbase;
    if (threadIdx.x == 0) lcnt = 0;
    __syncthreads();
    int i = blockIdx.x * 256 + threadIdx.x;
    int s = -1, lidx = 0, h = 0;
    if (i < DP) {
        s = slot[nodes[i]];
        if (s >= 0) {
            h = heBase + he[i];
            heneed[h] = 1;
            atomicAdd(&sdeg[s], 1.0f);
            lidx = atomicAdd(&lcnt, 1);
        }
    }
    __syncthreads();
    if (threadIdx.x == 0) lbase = (lcnt > 0) ? atomicAdd(mcnt, lcnt) : 0;
    __syncthreads();
    if (s >= 0) {
        int idx = lbase + lidx;
        if (idx < MCAP) { mhe[idx] = h; msl[idx] = s; }
    }
}

// both sides in one launch
__global__ void k_accmatch2(const float* __restrict__ efeat,
                            const int* __restrict__ mhe_s, const int* __restrict__ msl_s,
                            const int* __restrict__ mhe_k, const int* __restrict__ msl_k,
                            const int* __restrict__ mcnt,
                            float* sacc_s, float* sacc_k)
{
    int lane = threadIdx.x & 63;
    int w = (blockIdx.x * blockDim.x + threadIdx.x) >> 6;
    int nw = (gridDim.x * blockDim.x) >> 6;
    int Ms = min(mcnt[0], MCAP), Mk = min(mcnt[1], MCAP);
    for (int i = w; i < Ms + Mk; i += nw) {
        bool sess = i < Ms;
        int he = sess ? mhe_s[i] : mhe_k[i - Ms];
        int sl = sess ? msl_s[i] : msl_k[i - Ms];
        float* sacc = sess ? sacc_s : sacc_k;
        float2 v = *(const float2*)&efeat[(size_t)he * 128 + lane * 2];
        atomicAdd(&sacc[(size_t)sl * 128 + lane * 2],     v.x);
        atomicAdd(&sacc[(size_t)sl * 128 + lane * 2 + 1], v.y);
    }
}

// both sides in one launch
__global__ void k_rel_gather2(const float* __restrict__ so_s, const float* __restrict__ so_k,
                              const int* __restrict__ slot_s, const int* __restrict__ slot_k,
                              const int* __restrict__ ridx_s, const int* __restrict__ ridx_k,
                              float* __restrict__ related)
{
    int gid = blockIdx.x * blockDim.x + threadIdx.x;
    int i = gid >> 5, c = gid & 31;
    if (i >= 2 * DB * DLR) return;
    bool sess = i < DB * DLR;
    int ii = sess ? i : i - DB * DLR;
    int s = sess ? slot_s[ridx_s[ii]] : slot_k[ridx_k[ii]];
    const float* so = sess ? so_s : so_k;
    int b = ii / DLR, l = ii % DLR;
    int colOff = sess ? 0 : 64;
    ((float4*)&related[((size_t)b * 128 + colOff + l) * 128])[c] =
        ((const float4*)&so[(size_t)s * 128])[c];
}

// ---------------------------------------------------------------- gathers / misc
__global__ void k_gather_rows(const float* __restrict__ src, const int* __restrict__ idx,
                              float* dst, int nRows)
{
    int i = blockIdx.x * blockDim.x + threadIdx.x;
    if (i >= nRows * 128) return;
    int row = i >> 7, d = i & 127;
    dst[i] = src[(size_t)idx[row] * 128 + d];
}

// ---------------------------------------------------------------- MHA: one block per (b,h)
__global__ __launch_bounds__(256) void k_mha(const float* __restrict__ qb,
                                             const float* __restrict__ kb,
                                             const float* __restrict__ vb,
                                             float* __restrict__ ob)
{
    int b = blockIdx.x >> 3, h = blockIdx.x & 7;
    __shared__ float Ks[128][16], Vs[128][16], Qs[32][16];
    int tid = threadIdx.x;
    for (int i = tid; i < 128 * 16; i += 256) {
        int j = i >> 4, d = i & 15;
        Ks[j][d] = kb[((size_t)b * 128 + j) * 128 + h * 16 + d];
        Vs[j][d] = vb[((size_t)b * 128 + j) * 128 + h * 16 + d];
    }
    for (int i = tid; i < 32 * 16; i += 256) {
        int q = i >> 4, d = i & 15;
        Qs[q][d] = qb[((size_t)b * 32 + q) * 128 + h * 16 + d] * 0.25f;
    }
    __syncthreads();
    int q = tid >> 3;
    int jg = tid & 7;
    float lg[16];
    float m = -1e30f;
    #pragma unroll
    for (int jj = 0; jj < 16; ++jj) {
        int j = jg * 16 + jj;
        float s = 0.f;
        #pragma unroll
        for (int d = 0; d < 16; ++d) s += Qs[q][d] * Ks[j][d];
        lg[jj] = s;
        m = fmaxf(m, s);
    }
    #pragma unroll
    for (int o = 1; o < 8; o <<= 1) m = fmaxf(m, __shfl_xor(m, o));
    float sum = 0.f;
    float acc[16] = {};
    #pragma unroll
    for (int jj = 0; jj < 16; ++jj) {
        float p = __expf(lg[jj] - m);
        sum += p;
        int j = jg * 16 + jj;
        #pragma unroll
        for (int d = 0; d < 16; ++d) acc[d] += p * Vs[j][d];
    }
    #pragma unroll
    for (int o = 1; o < 8; o <<= 1) {
        sum += __shfl_xor(sum, o);
        #pragma unroll
        for (int d = 0; d < 16; ++d) acc[d] += __shfl_xor(acc[d], o);
    }
    if (jg == 0) {
        float inv = 1.0f / sum;
        #pragma unroll
        for (int d = 0; d < 16; ++d)
            ob[((size_t)b * 32 + q) * 128 + h * 16 + d] = acc[d] * inv;
    }
}

// ---------------------------------------------------------------- launch
extern "C" void kernel_launch(void* const* d_in, const int* in_sizes, int n_in,
                              void* d_out, int out_size, void* d_ws, size_t ws_size,
                              hipStream_t stream)
{
    const float* emb        = (const float*)d_in[0];
    const float* bases      = (const float*)d_in[1];
    const float* comp       = (const float*)d_in[2];
    const float* root       = (const float*)d_in[3];
    const float* rgcn_bias  = (const float*)d_in[4];
    const float* sess_theta = (const float*)d_in[5];
    const float* sess_bias  = (const float*)d_in[6];
    const float* know_theta = (const float*)d_in[7];
    const float* know_bias  = (const float*)d_in[8];
    const float* in_proj_w  = (const float*)d_in[9];
    const float* in_proj_b  = (const float*)d_in[10];
    const float* out_proj_w = (const float*)d_in[11];
    const float* out_proj_b = (const float*)d_in[12];
    const float* attn_his_a = (const float*)d_in[13];
    const float* attn_his_b = (const float*)d_in[14];
    const float* attn_a     = (const float*)d_in[15];
    const float* attn_b     = (const float*)d_in[16];
    const float* rec_bias   = (const float*)d_in[17];
    const int* edge_src     = (const int*)d_in[18];
    const int* edge_dst     = (const int*)d_in[19];
    const int* edge_type    = (const int*)d_in[20];
    const int* sess_nodes   = (const int*)d_in[21];
    const int* sess_edges   = (const int*)d_in[22];
    const int* know_nodes   = (const int*)d_in[23];
    const int* know_edges   = (const int*)d_in[24];
    const int* sess_rel_idx = (const int*)d_in[25];
    const int* know_rel_idx = (const int*)d_in[26];
    const int* context_idx  = (const int*)d_in[27];
    float* out = (float*)d_out;

    float* wsf = (float*)d_ws;
    size_t off = 0;
    auto alloc = [&](size_t n) { size_t r = off; off += (n + 255) & ~(size_t)255; return r; };
    float* kg      = wsf + alloc(12800000);          // N*D
    float* tmp     = wsf + alloc(12800000);          // RGCN sort arena + efeat + split arenas tail
    ushortT* warena = (ushortT*)(wsf + alloc(196608)); // 12 x 64KB split w[r]
    int*   bsumV   = (int*)(wsf + alloc(2048));
    int*   bsumP   = (int*)(wsf + alloc(2048));
    int*   stybase = (int*)(wsf + alloc(16));
    // ---- contiguous zero block (one memset) ----
    size_t zstart = off;
    int*   hhist   = (int*)(wsf + alloc(DHE2));
    int*   hcur    = (int*)(wsf + alloc(DHE2));
    int*   heneed  = (int*)(wsf + alloc(DHE2));
    int*   mcnt    = (int*)(wsf + alloc(16));        // [0]=sess, [1]=know
    int*   scnt    = (int*)(wsf + alloc(16));
    float* sdeg_s  = wsf + alloc(4096);
    float* sdeg_k  = wsf + alloc(4096);
    float* sacc_s  = wsf + alloc(524288);
    float* sacc_k  = wsf + alloc(524288);
    size_t zend = off;
    // ---- contiguous 0xFF block (one memset) ----
    size_t fstart = off;
    int*   slot_s  = (int*)(wsf + alloc(100000));
    int*   slot_k  = (int*)(wsf + alloc(100000));
    size_t fend = off;
    int*   hoff    = (int*)(wsf + alloc(DHE2));
    int*   pns     = (int*)(wsf + alloc(2 * DP));
    int*   mhe_s   = (int*)(wsf + alloc(MCAP));
    int*   msl_s   = (int*)(wsf + alloc(MCAP));
    int*   mhe_k   = (int*)(wsf + alloc(MCAP));
    int*   msl_k   = (int*)(wsf + alloc(MCAP));
    float* so_s    = wsf + alloc(524288);
    float* so_k    = wsf + alloc(524288);
    float* related = wsf + alloc(1048576);
    float* ctx     = wsf + alloc(262144);
    float* qb      = wsf + alloc(262144);
    float* kb      = wsf + alloc(1048576);
    float* vb      = wsf + alloc(1048576);
    float* obuf    = wsf + alloc(262144);
    float* attrel  = wsf + alloc(262144);
    float* his     = wsf + alloc(8192);
    float* ucat    = wsf + alloc(270336);
    float* userb   = wsf + alloc(8192);
    float* e1      = wsf + alloc(2048);
    float* e2      = wsf + alloc(2112);
    (void)ws_size; (void)in_sizes; (void)n_in; (void)out_size;

    // RGCN sort arena inside tmp; efeat (40000*128 = 5.12M) in the tail;
    // split-weight arenas in the dead tail after efeat (tmp used: 12.42M of 12.8M floats)
    int*   hist    = (int*)tmp;                 // 1.2M
    int*   rcur    = (int*)tmp + 1200000;       // 1.2M (bucket cursor, pre-zeroed with hist)
    int*   soff    = (int*)tmp + 2400000;       // 1.2M
    int*   segpos  = (int*)tmp + 3600000;       // 1.2M
    int*   seglist = (int*)tmp + 4800000;       // 1.2M
    int*   ssrc    = (int*)tmp + 6000000;       // 1.0M
    float* efeat   = tmp + 7000000;             // 5.12M (used only after RGCN finishes)
    ushortT* wsplit = (ushortT*)(tmp + 12200000); // 9 x 32768 ushorts = 147456 floats
    ushortT* usplit = (ushortT*)(tmp + 12400000); // 16384 ushorts = 8192 floats

    const int nbR = (NRBINS + SCAN_CHUNK - 1) / SCAN_CHUNK;   // 1172
    const int nbH = (DHE2 + SCAN_CHUNK - 1) / SCAN_CHUNK;     // 40

    // ---------------- upfront memsets (3 total)
    hipMemsetAsync(wsf + zstart, 0, (zend - zstart) * 4, stream);
    hipMemsetAsync(wsf + fstart, 0xFF, (fend - fstart) * 4, stream);
    hipMemsetAsync(hist, 0, 2400000 * 4, stream);   // hist + rcur

    // weight pre-split (independent of everything else)
    k_presplit_all<<<576, 256, 0, stream>>>(root, sess_theta, know_theta, in_proj_w,
                                            out_proj_w, attn_his_a, attn_a, wsplit);

    k_slot_assign2<<<32, 256, 0, stream>>>(sess_rel_idx, know_rel_idx, slot_s, slot_k, scnt);
    // sdeg/match/need-flags early (only depend on slot arrays)
    k_sdeg_match<<<(DP + 255) / 256, 256, 0, stream>>>(sess_nodes, sess_edges, slot_s,
                                                       sdeg_s, mcnt, mhe_s, msl_s, heneed, 0);
    k_sdeg_match<<<(DP + 255) / 256, 256, 0, stream>>>(know_nodes, know_edges, slot_k,
                                                       sdeg_k, mcnt + 1, mhe_k, msl_k, heneed, DHE);

    // ---------------- RGCN: sort edges by (type, dst)
    k_hist_rgcn<<<(DE + 255) / 256, 256, 0, stream>>>(edge_dst, edge_type, hist, DE);
    k_scan2_pass1<<<nbR, 256, 0, stream>>>(hist, NRBINS, bsumV, bsumP);
    k_scan2_pass2<<<1, 256, 0, stream>>>(bsumV, bsumP, nbR, stybase + DR);
    k_scan2_pass3<<<nbR, 256, 0, stream>>>(hist, NRBINS, bsumV, bsumP, soff, segpos);
    k_stypebase<<<1, 64, 0, stream>>>(segpos, stybase);
    k_seglist<<<(NRBINS + 255) / 256, 256, 0, stream>>>(hist, segpos, seglist, NRBINS);
    k_bucket_rgcn<<<(DE + 255) / 256, 256, 0, stream>>>(edge_src, edge_dst, edge_type,
                                                        soff, rcur, ssrc, DE);
    k_wcomp_split<<<(DR * DD * DD + 255) / 256, 256, 0, stream>>>(comp, bases, warena);

    int gemmN = (DN + 63) / 64;
    k_gemm_ds<<<gemmN, 256, 0, stream>>>(emb, wsplit + 0 * 32768, rgcn_bias, nullptr, kg, DN);
    for (int r = 0; r < DR; ++r)
        k_rgcn_ds<<<gemmN, 256, 0, stream>>>(emb, warena, seglist, soff, hist, ssrc,
                                             stybase, kg, r);

    // ---------------- hypergraph (both sides as one 40000-edge problem)
    k_hist_p2<<<(2 * DP + 255) / 256, 256, 0, stream>>>(sess_edges, know_edges, hhist);
    k_scan_pass1<<<nbH, 256, 0, stream>>>(hhist, DHE2, bsumV);
    k_scan_pass2p<<<1, 256, 0, stream>>>(bsumV, nbH, nullptr);
    k_scan_pass3<<<nbH, 256, 0, stream>>>(hhist, DHE2, bsumV, hoff);
    k_bucket_p2<<<(2 * DP + 255) / 256, 256, 0, stream>>>(sess_nodes, sess_edges,
                                                          know_nodes, know_edges,
                                                          hoff, hcur, pns);
    k_hyper_agg<<<(DHE2 * 64 + 255) / 256, 256, 0, stream>>>(kg, pns, hoff, hhist, heneed, efeat);
    k_accmatch2<<<256, 256, 0, stream>>>(efeat, mhe_s, msl_s, mhe_k, msl_k, mcnt, sacc_s, sacc_k);

    k_gemm_ds<<<64, 256, 0, stream>>>(sacc_s, wsplit + 1 * 32768, sess_bias, sdeg_s, so_s, 4096);
    k_gemm_ds<<<64, 256, 0, stream>>>(sacc_k, wsplit + 2 * 32768, know_bias, sdeg_k, so_k, 4096);
    k_rel_gather2<<<(2 * DB * DLR * 32 + 255) / 256, 256, 0, stream>>>(
        so_s, so_k, slot_s, slot_k, sess_rel_idx, know_rel_idx, related);

    // ---------------- context + MHA
    k_gather_rows<<<(DB * DLC * 128 + 255) / 256, 256, 0, stream>>>(kg, context_idx, ctx, DB * DLC);
    k_gemm_ds<<<(DB * DLC + 63) / 64, 256, 0, stream>>>(ctx, wsplit + 3 * 32768,
                                                        in_proj_b, nullptr, qb, DB * DLC);
    k_gemm_ds<<<(DB * 128 + 63) / 64, 256, 0, stream>>>(related, wsplit + 4 * 32768,
                                                        in_proj_b + DD, nullptr, kb, DB * 128);
    k_gemm_ds<<<(DB * 128 + 63) / 64, 256, 0, stream>>>(related, wsplit + 5 * 32768,
                                                        in_proj_b + 2 * DD, nullptr, vb, DB * 128);
    k_mha<<<DB * DNH, 256, 0, stream>>>(qb, kb, vb, obuf);
    k_gemm_ds<<<(DB * DLC + 63) / 64, 256, 0, stream>>>(obuf, wsplit + 6 * 32768,
                                                        out_proj_b, nullptr, attrel, DB * DLC);

    // ---------------- pooling (GEMM-shaped) + score
    k_tanh_dot_ds<<<(DB * DLC + 63) / 64, 256, 0, stream>>>(attrel, wsplit + 7 * 32768,
                                                            attn_his_b, e1, DB * DLC);
    k_pool_apply<32><<<DB, 128, 0, stream>>>(attrel, e1, his, nullptr);
    k_build_ucat<<<(DB * 33 * 128 + 255) / 256, 256, 0, stream>>>(ctx, his, ucat);
    k_tanh_dot_ds<<<(DB * 33 + 63) / 64, 256, 0, stream>>>(ucat, wsplit + 8 * 32768,
                                                           attn_b, e2, DB * 33);
    k_pool_apply<33><<<DB, 128, 0, stream>>>(ucat, e2, userb, usplit);
    k_score_ds<<<gemmN, 256, 0, stream>>>(kg, usplit, rec_bias, out);
}

// Round 4
// 968.060 us; speedup vs baseline: 1.1310x; 1.0178x over previous
//
#include <hip/hip_runtime.h>
#include <hip/hip_bf16.h>

#define DN 100000     // N entities
#define DD 128        // D
#define DR 12         // R relations
#define DNB 8         // bases
#define DE 1000000    // edges
#define DP 400000     // hyperedge incidences
#define DHE 20000     // hyperedges
#define DHE2 40000    // both sides combined
#define DB 64         // batch
#define DLR 64
#define DLC 32
#define DNH 8
#define DHD 16
#define NRBINS (DR * DN)   // 1.2M
#define SCAN_CHUNK 1024
#define MCAP 65536

typedef unsigned short ushortT;
typedef unsigned int uintT;
typedef __attribute__((ext_vector_type(8))) short s8v;
typedef __attribute__((ext_vector_type(4))) float f4v;

#define APAD 136   // 64 rows of K=128 bf16, stride 272B

__device__ __forceinline__ ushortT rneb(float v) {
    uintT b = __float_as_uint(v);
    return (ushortT)((b + 0x7FFFu + ((b >> 16) & 1u)) >> 16);
}
__device__ __forceinline__ float b2f(ushortT h) {
    return __uint_as_float(((uintT)h) << 16);
}

__device__ __forceinline__ void split_store8(ushortT* hbase, ushortT* lbase, const float* v)
{
    ushortT h[8], l[8];
    #pragma unroll
    for (int j = 0; j < 8; ++j) {
        h[j] = rneb(v[j]);
        l[j] = rneb(v[j] - b2f(h[j]));
    }
    uint4 hv = make_uint4((uintT)h[0] | ((uintT)h[1] << 16), (uintT)h[2] | ((uintT)h[3] << 16),
                          (uintT)h[4] | ((uintT)h[5] << 16), (uintT)h[6] | ((uintT)h[7] << 16));
    uint4 lv = make_uint4((uintT)l[0] | ((uintT)l[1] << 16), (uintT)l[2] | ((uintT)l[3] << 16),
                          (uintT)l[4] | ((uintT)l[5] << 16), (uintT)l[6] | ((uintT)l[7] << 16));
    *(uint4*)hbase = hv;
    *(uint4*)lbase = lv;
}

// ---------------------------------------------------------------- weight pre-split (blocked fragment layout)
// WB[kc][n][k] (k in [0,32), n in [0,N)) ushort, h plane then l plane at +4*N*32.
// 0 root(t0) 1 sess_theta(t0) 2 know_theta(t0) 3 wq(t1) 4 wk(t1) 5 wv(t1)
// 6 out_proj(t1) 7 attn_his_a(t0) 8 attn_a(t0)
__global__ __launch_bounds__(256) void k_presplit_all(
    const float* __restrict__ root, const float* __restrict__ st,
    const float* __restrict__ kt, const float* __restrict__ ipw,
    const float* __restrict__ opw, const float* __restrict__ aha,
    const float* __restrict__ aa, ushortT* __restrict__ outA)
{
    int gid = blockIdx.x * 256 + threadIdx.x;   // 9*16384 exact
    int mat = gid >> 14, e = gid & 16383;
    const float* srcs[9] = {root, st, kt, ipw, ipw + 16384, ipw + 32768, opw, aha, aa};
    const float* W = srcs[mat];
    bool t1 = (mat >= 3 && mat <= 6);
    int k = e & 31, n = (e >> 5) & 127, kc = e >> 12;
    float f = t1 ? W[(size_t)n * 128 + kc * 32 + k] : W[(size_t)(kc * 32 + k) * 128 + n];
    ushortT h = rneb(f);
    outA[(size_t)mat * 32768 + e] = h;
    outA[(size_t)mat * 32768 + 16384 + e] = rneb(f - b2f(h));
}

// w[r] = comp[r]·bases, split directly into blocked layout (64KB per r: h 32KB, l 32KB)
__global__ void k_wcomp_split(const float* __restrict__ comp, const float* __restrict__ bases,
                              ushortT* __restrict__ warena)
{
    int i = blockIdx.x * blockDim.x + threadIdx.x;
    if (i >= DR * DD * DD) return;
    int r = i / (DD * DD), io = i % (DD * DD);
    float s = 0.f;
    #pragma unroll
    for (int b = 0; b < DNB; ++b) s += comp[r * DNB + b] * bases[(size_t)b * DD * DD + io];
    int irow = io >> 7, o = io & 127;          // w[r][irow][o], irow = k-dim
    int kc = irow >> 5, k = irow & 31;
    size_t dst = (size_t)r * 32768 + (size_t)kc * 4096 + o * 32 + k;
    ushortT h = rneb(s);
    warena[dst] = h;
    warena[dst + 16384] = rneb(s - b2f(h));
}

// ---------------------------------------------------------------- MFMA GEMM, B copy-staged per kc from pre-split global
// optional gidx: A-row indirection (gather); optional gout: write gathered rows
__global__ __launch_bounds__(256) void k_gemm_ds(
    const float* __restrict__ A, const ushortT* __restrict__ Wb,
    const float* __restrict__ bias, const float* __restrict__ rs,
    const int* __restrict__ gidx, float* __restrict__ gout,
    float* __restrict__ C, int M)
{
    __shared__ __align__(16) ushortT Ah[64 * APAD], Al[64 * APAD];
    __shared__ __align__(16) ushortT Bs[8192];   // h [0,4096), l [4096,8192) for current kc
    int tid = threadIdx.x;
    int row0 = blockIdx.x * 64;
    {
        int row = tid >> 2, c0 = (tid & 3) * 32;
        int gr = row0 + row;
        int arow = gr;
        if (gidx && gr < M) arow = gidx[gr];
        const float* ar = A + (size_t)arow * 128 + c0;
        float sc = 1.0f;
        if (rs && gr < M) { float d = rs[gr]; sc = (d > 0.f) ? 1.0f / d : 0.f; }
        #pragma unroll
        for (int g = 0; g < 4; ++g) {
            float v[8] = {};
            if (gr < M) {
                float4 u0 = *(const float4*)(ar + g * 8);
                float4 u1 = *(const float4*)(ar + g * 8 + 4);
                v[0]=u0.x*sc; v[1]=u0.y*sc; v[2]=u0.z*sc; v[3]=u0.w*sc;
                v[4]=u1.x*sc; v[5]=u1.y*sc; v[6]=u1.z*sc; v[7]=u1.w*sc;
                if (gout) {
                    *(float4*)(gout + (size_t)gr * 128 + c0 + g * 8)     = u0;
                    *(float4*)(gout + (size_t)gr * 128 + c0 + g * 8 + 4) = u1;
                }
            }
            split_store8(&Ah[row * APAD + c0 + g * 8], &Al[row * APAD + c0 + g * 8], v);
        }
    }
    f4v acc[8] = {};
    int w = tid >> 6, lane = tid & 63, m = lane & 15, quad = lane >> 4;
    for (int kc = 0; kc < 4; ++kc) {
        __syncthreads();
        {   // pure-copy stage of B kc-slab: 8KB h + 8KB l
            const ushortT* gh = Wb + kc * 4096;
            const ushortT* gl = Wb + 16384 + kc * 4096;
            *(s8v*)&Bs[tid * 8]        = *(const s8v*)&gh[tid * 8];
            *(s8v*)&Bs[2048 + tid * 8] = *(const s8v*)&gh[2048 + tid * 8];
            *(s8v*)&Bs[4096 + tid * 8] = *(const s8v*)&gl[tid * 8];
            *(s8v*)&Bs[6144 + tid * 8] = *(const s8v*)&gl[2048 + tid * 8];
        }
        __syncthreads();
        s8v ah = *(const s8v*)&Ah[(w * 16 + m) * APAD + kc * 32 + quad * 8];
        s8v al = *(const s8v*)&Al[(w * 16 + m) * APAD + kc * 32 + quad * 8];
        #pragma unroll
        for (int nt = 0; nt < 8; ++nt) {
            int boff = (nt * 16 + m) * 32 + quad * 8;
            s8v bh = *(const s8v*)&Bs[boff];
            s8v bl = *(const s8v*)&Bs[4096 + boff];
            acc[nt] = __builtin_amdgcn_mfma_f32_16x16x32_bf16(ah, bh, acc[nt], 0, 0, 0);
            acc[nt] = __builtin_amdgcn_mfma_f32_16x16x32_bf16(al, bh, acc[nt], 0, 0, 0);
            acc[nt] = __builtin_amdgcn_mfma_f32_16x16x32_bf16(ah, bl, acc[nt], 0, 0, 0);
        }
    }
    float bv[8];
    #pragma unroll
    for (int nt = 0; nt < 8; ++nt) bv[nt] = bias ? bias[nt * 16 + m] : 0.f;
    #pragma unroll
    for (int rr = 0; rr < 4; ++rr) {
        int gr = row0 + w * 16 + quad * 4 + rr;
        if (gr < M) {
            #pragma unroll
            for (int nt = 0; nt < 8; ++nt)
                C[(size_t)gr * 128 + nt * 16 + m] = acc[nt][rr] + bv[nt];
        }
    }
}

// ---------------------------------------------------------------- fused e[row] = tanh(A@W)[row,:] . bvec
__global__ __launch_bounds__(256) void k_tanh_dot_ds(
    const float* __restrict__ A, const ushortT* __restrict__ Wb,
    const float* __restrict__ bvec, float* __restrict__ e, int M)
{
    __shared__ __align__(16) ushortT Ah[64 * APAD], Al[64 * APAD];
    __shared__ __align__(16) ushortT Bs[8192];
    int tid = threadIdx.x;
    int row0 = blockIdx.x * 64;
    {
        int row = tid >> 2, c0 = (tid & 3) * 32;
        int gr = row0 + row;
        const float* ar = A + (size_t)gr * 128 + c0;
        #pragma unroll
        for (int g = 0; g < 4; ++g) {
            float v[8] = {};
            if (gr < M) {
                float4 u0 = *(const float4*)(ar + g * 8);
                float4 u1 = *(const float4*)(ar + g * 8 + 4);
                v[0]=u0.x; v[1]=u0.y; v[2]=u0.z; v[3]=u0.w;
                v[4]=u1.x; v[5]=u1.y; v[6]=u1.z; v[7]=u1.w;
            }
            split_store8(&Ah[row * APAD + c0 + g * 8], &Al[row * APAD + c0 + g * 8], v);
        }
    }
    f4v acc[8] = {};
    int w = tid >> 6, lane = tid & 63, m = lane & 15, quad = lane >> 4;
    for (int kc = 0; kc < 4; ++kc) {
        __syncthreads();
        {
            const ushortT* gh = Wb + kc * 4096;
            const ushortT* gl = Wb + 16384 + kc * 4096;
            *(s8v*)&Bs[tid * 8]        = *(const s8v*)&gh[tid * 8];
            *(s8v*)&Bs[2048 + tid * 8] = *(const s8v*)&gh[2048 + tid * 8];
            *(s8v*)&Bs[4096 + tid * 8] = *(const s8v*)&gl[tid * 8];
            *(s8v*)&Bs[6144 + tid * 8] = *(const s8v*)&gl[2048 + tid * 8];
        }
        __syncthreads();
        s8v ah = *(const s8v*)&Ah[(w * 16 + m) * APAD + kc * 32 + quad * 8];
        s8v al = *(const s8v*)&Al[(w * 16 + m) * APAD + kc * 32 + quad * 8];
        #pragma unroll
        for (int nt = 0; nt < 8; ++nt) {
            int boff = (nt * 16 + m) * 32 + quad * 8;
            s8v bh = *(const s8v*)&Bs[boff];
            s8v bl = *(const s8v*)&Bs[4096 + boff];
            acc[nt] = __builtin_amdgcn_mfma_f32_16x16x32_bf16(ah, bh, acc[nt], 0, 0, 0);
            acc[nt] = __builtin_amdgcn_mfma_f32_16x16x32_bf16(al, bh, acc[nt], 0, 0, 0);
            acc[nt] = __builtin_amdgcn_mfma_f32_16x16x32_bf16(ah, bl, acc[nt], 0, 0, 0);
        }
    }
    float bv[8];
    #pragma unroll
    for (int nt = 0; nt < 8; ++nt) bv[nt] = bvec[nt * 16 + m];
    #pragma unroll
    for (int rr = 0; rr < 4; ++rr) {
        float p = 0.f;
        #pragma unroll
        for (int nt = 0; nt < 8; ++nt) p += tanhf(acc[nt][rr]) * bv[nt];
        #pragma unroll
        for (int o = 1; o < 16; o <<= 1) p += __shfl_xor(p, o);
        int gr = row0 + w * 16 + quad * 4 + rr;
        if (m == 0 && gr < M) e[gr] = p;
    }
}

// ---------------------------------------------------------------- softmax(e) weighted sum of h rows (+ optional user split)
template <int L>
__global__ __launch_bounds__(128) void k_pool_apply(const float* __restrict__ h,
                                                    const float* __restrict__ e,
                                                    float* __restrict__ out,
                                                    ushortT* __restrict__ us)
{
    __shared__ float es[L];
    int b = blockIdx.x, tid = threadIdx.x;
    if (tid < L) es[tid] = e[b * L + tid];
    __syncthreads();
    float mx = -1e30f;
    #pragma unroll
    for (int l = 0; l < L; ++l) mx = fmaxf(mx, es[l]);
    float wgt[L];
    float sum = 0.f;
    #pragma unroll
    for (int l = 0; l < L; ++l) { wgt[l] = __expf(es[l] - mx); sum += wgt[l]; }
    float inv = 1.0f / sum;
    float o = 0.f;
    #pragma unroll
    for (int l = 0; l < L; ++l) o += wgt[l] * h[((size_t)b * L + l) * 128 + tid];
    float val = o * inv;
    out[(size_t)b * 128 + tid] = val;
    if (us) {   // split directly into blocked [kc][64][32] layout, l plane at +8192
        ushortT hh = rneb(val);
        ushortT ll = rneb(val - b2f(hh));
        int e_ = ((tid >> 5) * 2048) + b * 32 + (tid & 31);
        us[e_] = hh;
        us[8192 + e_] = ll;
    }
}

__global__ void k_build_ucat(const float* __restrict__ ctx, const float* __restrict__ his,
                             float* ucat)
{
    int i = blockIdx.x * blockDim.x + threadIdx.x;
    if (i >= DB * 33 * 128) return;
    int d = i & 127, l = (i >> 7) % 33, b = i / (33 * 128);
    ucat[i] = (l < 32) ? ctx[((size_t)b * 32 + l) * 128 + d] : his[(size_t)b * 128 + d];
}

// ---------------------------------------------------------------- RGCN: ALL relations in one launch
// block -> r via bo[] prefix table; output via atomicAdd (blocks of different r may share dst)
__global__ __launch_bounds__(256) void k_rgcn_all(
    const float* __restrict__ x, const ushortT* __restrict__ warena,
    const int* __restrict__ seglist, const int* __restrict__ soff,
    const int* __restrict__ slen, const int* __restrict__ ssrc,
    const int* __restrict__ stypebase, const int* __restrict__ bo,
    float* __restrict__ kg)
{
    __shared__ __align__(16) ushortT Ah[64 * APAD], Al[64 * APAD];
    __shared__ __align__(16) ushortT Bs[8192];
    int bid = blockIdx.x;
    if (bid >= bo[DR]) return;
    int r = 0;
    #pragma unroll 1
    while (bid >= bo[r + 1]) ++r;
    int s0 = stypebase[r], s1 = stypebase[r + 1];
    int base = s0 + (bid - bo[r]) * 64;
    int nrow = min(64, s1 - base);
    int tid = threadIdx.x;
    const ushortT* Wb = warena + (size_t)r * 32768;
    {
        int row = tid >> 2, c0 = (tid & 3) * 32;
        float a[32] = {};
        if (row < nrow) {
            int key = seglist[base + row];
            int len = slen[key];
            int st = soff[key] - len;   // soff was incremented in-place during bucketing
            for (int i = 0; i < len; ++i) {
                const float* xr = x + (size_t)ssrc[st + i] * 128 + c0;
                #pragma unroll
                for (int j = 0; j < 8; ++j) {
                    float4 v = *(const float4*)(xr + j * 4);
                    a[j*4+0] += v.x; a[j*4+1] += v.y; a[j*4+2] += v.z; a[j*4+3] += v.w;
                }
            }
            float inv = 1.0f / (float)max(len, 1);
            #pragma unroll
            for (int j = 0; j < 32; ++j) a[j] *= inv;
        }
        #pragma unroll
        for (int g = 0; g < 4; ++g)
            split_store8(&Ah[row * APAD + c0 + g * 8], &Al[row * APAD + c0 + g * 8], a + g * 8);
    }
    f4v acc[8] = {};
    int w = tid >> 6, lane = tid & 63, m = lane & 15, quad = lane >> 4;
    for (int kc = 0; kc < 4; ++kc) {
        __syncthreads();
        {
            const ushortT* gh = Wb + kc * 4096;
            const ushortT* gl = Wb + 16384 + kc * 4096;
            *(s8v*)&Bs[tid * 8]        = *(const s8v*)&gh[tid * 8];
            *(s8v*)&Bs[2048 + tid * 8] = *(const s8v*)&gh[2048 + tid * 8];
            *(s8v*)&Bs[4096 + tid * 8] = *(const s8v*)&gl[tid * 8];
            *(s8v*)&Bs[6144 + tid * 8] = *(const s8v*)&gl[2048 + tid * 8];
        }
        __syncthreads();
        s8v ah = *(const s8v*)&Ah[(w * 16 + m) * APAD + kc * 32 + quad * 8];
        s8v al = *(const s8v*)&Al[(w * 16 + m) * APAD + kc * 32 + quad * 8];
        #pragma unroll
        for (int nt = 0; nt < 8; ++nt) {
            int boff = (nt * 16 + m) * 32 + quad * 8;
            s8v bh = *(const s8v*)&Bs[boff];
            s8v bl = *(const s8v*)&Bs[4096 + boff];
            acc[nt] = __builtin_amdgcn_mfma_f32_16x16x32_bf16(ah, bh, acc[nt], 0, 0, 0);
            acc[nt] = __builtin_amdgcn_mfma_f32_16x16x32_bf16(al, bh, acc[nt], 0, 0, 0);
            acc[nt] = __builtin_amdgcn_mfma_f32_16x16x32_bf16(ah, bl, acc[nt], 0, 0, 0);
        }
    }
    #pragma unroll
    for (int rr = 0; rr < 4; ++rr) {
        int rt = w * 16 + quad * 4 + rr;
        if (rt < nrow) {
            int dst = seglist[base + rt] - r * DN;
            float* kr = kg + (size_t)dst * 128 + m;
            #pragma unroll
            for (int nt = 0; nt < 8; ++nt)
                atomicAdd(&kr[nt * 16], acc[nt][rr]);
        }
    }
}

// ---------------------------------------------------------------- scoring (MFMA, B copy-staged from pre-split user)
__global__ __launch_bounds__(256) void k_score_ds(
    const float* __restrict__ kg, const ushortT* __restrict__ Ub,
    const float* __restrict__ rb, float* __restrict__ out)
{
    __shared__ __align__(16) ushortT Ah[64 * APAD], Al[64 * APAD];
    __shared__ __align__(16) ushortT Bs[4096];   // h [0,2048), l [2048,4096) for current kc
    int tid = threadIdx.x;
    int n0 = blockIdx.x * 64;
    {
        int row = tid >> 2, c0 = (tid & 3) * 32;
        int gr = n0 + row;
        const float* ar = kg + (size_t)gr * 128 + c0;
        #pragma unroll
        for (int g = 0; g < 4; ++g) {
            float v[8] = {};
            if (gr < DN) {
                float4 u0 = *(const float4*)(ar + g * 8);
                float4 u1 = *(const float4*)(ar + g * 8 + 4);
                v[0]=u0.x; v[1]=u0.y; v[2]=u0.z; v[3]=u0.w;
                v[4]=u1.x; v[5]=u1.y; v[6]=u1.z; v[7]=u1.w;
            }
            split_store8(&Ah[row * APAD + c0 + g * 8], &Al[row * APAD + c0 + g * 8], v);
        }
    }
    f4v acc[4] = {};
    int w = tid >> 6, lane = tid & 63, m = lane & 15, quad = lane >> 4;
    for (int kc = 0; kc < 4; ++kc) {
        __syncthreads();
        {
            const ushortT* gh = Ub + kc * 2048;
            const ushortT* gl = Ub + 8192 + kc * 2048;
            *(s8v*)&Bs[tid * 8]        = *(const s8v*)&gh[tid * 8];
            *(s8v*)&Bs[2048 + tid * 8] = *(const s8v*)&gl[tid * 8];
        }
        __syncthreads();
        s8v ah = *(const s8v*)&Ah[(w * 16 + m) * APAD + kc * 32 + quad * 8];
        s8v al = *(const s8v*)&Al[(w * 16 + m) * APAD + kc * 32 + quad * 8];
        #pragma unroll
        for (int nt = 0; nt < 4; ++nt) {
            int boff = (nt * 16 + m) * 32 + quad * 8;
            s8v bh = *(const s8v*)&Bs[boff];
            s8v bl = *(const s8v*)&Bs[2048 + boff];
            acc[nt] = __builtin_amdgcn_mfma_f32_16x16x32_bf16(ah, bh, acc[nt], 0, 0, 0);
            acc[nt] = __builtin_amdgcn_mfma_f32_16x16x32_bf16(al, bh, acc[nt], 0, 0, 0);
            acc[nt] = __builtin_amdgcn_mfma_f32_16x16x32_bf16(ah, bl, acc[nt], 0, 0, 0);
        }
    }
    int n = n0 + w * 16 + quad * 4;
    if (n < DN) {
        float4 rbv = *(const float4*)&rb[n];
        #pragma unroll
        for (int nt = 0; nt < 4; ++nt) {
            int b = nt * 16 + m;
            float4 o = make_float4(acc[nt][0] + rbv.x, acc[nt][1] + rbv.y,
                                   acc[nt][2] + rbv.z, acc[nt][3] + rbv.w);
            *(float4*)&out[(size_t)b * DN + n] = o;
        }
    }
}

// ---------------------------------------------------------------- scans (single-mode, for hyper)
__global__ void k_scan_pass1(const int* __restrict__ in, int n, int* __restrict__ bsum)
{
    __shared__ int red[256];
    int b = blockIdx.x, t = threadIdx.x;
    int i0 = b * SCAN_CHUNK + t * 4;
    int s = 0;
    #pragma unroll
    for (int j = 0; j < 4; ++j) {
        int i = i0 + j;
        if (i < n) s += in[i];
    }
    red[t] = s;
    __syncthreads();
    for (int o = 128; o > 0; o >>= 1) {
        if (t < o) red[t] += red[t + o];
        __syncthreads();
    }
    if (t == 0) bsum[b] = red[0];
}

__global__ __launch_bounds__(256) void k_scan_pass2p(int* bsum, int nb, int* total)
{
    __shared__ int lds[256];
    __shared__ int carry;
    int t = threadIdx.x;
    if (t == 0) carry = 0;
    __syncthreads();
    for (int c0 = 0; c0 < nb; c0 += 256) {
        int i = c0 + t;
        int v = (i < nb) ? bsum[i] : 0;
        lds[t] = v;
        __syncthreads();
        for (int o = 1; o < 256; o <<= 1) {
            int add = (t >= o) ? lds[t - o] : 0;
            __syncthreads();
            lds[t] += add;
            __syncthreads();
        }
        int myc = carry;
        if (i < nb) bsum[i] = lds[t] - v + myc;
        int tot = lds[255];
        __syncthreads();
        if (t == 0) carry = myc + tot;
        __syncthreads();
    }
    if (total && t == 0) *total = carry;
}

__global__ void k_scan_pass3(const int* __restrict__ in, int n, const int* __restrict__ bsum,
                             int* __restrict__ out)
{
    __shared__ int lds[256];
    int b = blockIdx.x, t = threadIdx.x;
    int i0 = b * SCAN_CHUNK + t * 4;
    int v[4]; int s = 0;
    #pragma unroll
    for (int j = 0; j < 4; ++j) {
        int i = i0 + j;
        int x = 0;
        if (i < n) x = in[i];
        v[j] = x; s += x;
    }
    lds[t] = s;
    __syncthreads();
    for (int o = 1; o < 256; o <<= 1) {
        int add = (t >= o) ? lds[t - o] : 0;
        __syncthreads();
        lds[t] += add;
        __syncthreads();
    }
    int run = lds[t] - s + bsum[b];
    #pragma unroll
    for (int j = 0; j < 4; ++j) {
        int i = i0 + j;
        if (i < n) { out[i] = run; run += v[j]; }
    }
}

// ---------------------------------------------------------------- dual scan (value + predicate), for RGCN
__global__ void k_scan2_pass1(const int* __restrict__ in, int n, int* bV, int* bP)
{
    __shared__ int redV[256], redP[256];
    int b = blockIdx.x, t = threadIdx.x;
    int i0 = b * SCAN_CHUNK + t * 4;
    int sv = 0, sp = 0;
    #pragma unroll
    for (int j = 0; j < 4; ++j) {
        int i = i0 + j;
        if (i < n) { int v = in[i]; sv += v; sp += (v > 0); }
    }
    redV[t] = sv; redP[t] = sp;
    __syncthreads();
    for (int o = 128; o > 0; o >>= 1) {
        if (t < o) { redV[t] += redV[t + o]; redP[t] += redP[t + o]; }
        __syncthreads();
    }
    if (t == 0) { bV[b] = redV[0]; bP[b] = redP[0]; }
}

__global__ __launch_bounds__(256) void k_scan2_pass2(int* bV, int* bP, int nb, int* totalP)
{
    __shared__ int lds[256];
    __shared__ int carry;
    int t = threadIdx.x;
    #pragma unroll 1
    for (int which = 0; which < 2; ++which) {
        int* bsum = which ? bP : bV;
        __syncthreads();
        if (t == 0) carry = 0;
        __syncthreads();
        for (int c0 = 0; c0 < nb; c0 += 256) {
            int i = c0 + t;
            int v = (i < nb) ? bsum[i] : 0;
            lds[t] = v;
            __syncthreads();
            for (int o = 1; o < 256; o <<= 1) {
                int add = (t >= o) ? lds[t - o] : 0;
                __syncthreads();
                lds[t] += add;
                __syncthreads();
            }
            int myc = carry;
            if (i < nb) bsum[i] = lds[t] - v + myc;
            int tot = lds[255];
            __syncthreads();
            if (t == 0) carry = myc + tot;
            __syncthreads();
        }
        if (which == 1 && totalP && t == 0) *totalP = carry;
    }
}

__global__ void k_scan2_pass3(const int* __restrict__ in, int n,
                              const int* __restrict__ bV, const int* __restrict__ bP,
                              int* __restrict__ outV, int* __restrict__ outP)
{
    __shared__ int ldsV[256], ldsP[256];
    int b = blockIdx.x, t = threadIdx.x;
    int i0 = b * SCAN_CHUNK + t * 4;
    int v[4]; int sv = 0, sp = 0;
    #pragma unroll
    for (int j = 0; j < 4; ++j) {
        int i = i0 + j;
        int x = 0;
        if (i < n) x = in[i];
        v[j] = x; sv += x; sp += (x > 0);
    }
    ldsV[t] = sv; ldsP[t] = sp;
    __syncthreads();
    for (int o = 1; o < 256; o <<= 1) {
        int addV = (t >= o) ? ldsV[t - o] : 0;
        int addP = (t >= o) ? ldsP[t - o] : 0;
        __syncthreads();
        ldsV[t] += addV; ldsP[t] += addP;
        __syncthreads();
    }
    int runV = ldsV[t] - sv + bV[b];
    int runP = ldsP[t] - sp + bP[b];
    #pragma unroll
    for (int j = 0; j < 4; ++j) {
        int i = i0 + j;
        if (i < n) {
            outV[i] = runV; outP[i] = runP;
            runV += v[j]; runP += (v[j] > 0);
        }
    }
}

// ---------------------------------------------------------------- merged histogram (RGCN edges + both hyper sides)
__global__ void k_hist_both(const int* __restrict__ dst, const int* __restrict__ et,
                            int* __restrict__ hist,
                            const int* __restrict__ se, const int* __restrict__ ke,
                            int* __restrict__ hhist)
{
    int i = blockIdx.x * blockDim.x + threadIdx.x;
    if (i < DE) {
        atomicAdd(&hist[(size_t)et[i] * DN + dst[i]], 1);
    } else {
        int j = i - DE;
        if (j < DP) atomicAdd(&hhist[se[j]], 1);
        else if (j < 2 * DP) atomicAdd(&hhist[DHE + ke[j - DP]], 1);
    }
}

__global__ void k_seglist(const int* __restrict__ hist, const int* __restrict__ segpos,
                          int* __restrict__ seglist, int n)
{
    int i = blockIdx.x * blockDim.x + threadIdx.x;
    if (i < n && hist[i] > 0) seglist[segpos[i]] = i;
}

// stybase + block-offset prefix table (bo[r+1] = sum of ceil(seg_r/64))
__global__ void k_stypebase(const int* __restrict__ segpos, int* stybase, int* bo)
{
    int t = threadIdx.x;
    if (t < DR) stybase[t] = segpos[(size_t)t * DN];
    if (t == 0) {
        int acc = 0; bo[0] = 0;
        int prev = segpos[0];
        for (int r = 0; r < DR; ++r) {
            int nxt = (r == DR - 1) ? stybase[DR] : segpos[(size_t)(r + 1) * DN];
            acc += (nxt - prev + 63) >> 6;
            bo[r + 1] = acc;
            prev = nxt;
        }
    }
}

// merged bucket scatter (in-place cursor: pos = atomicAdd(&off[key],1))
__global__ void k_bucket_both(const int* __restrict__ src, const int* __restrict__ dst,
                              const int* __restrict__ et, int* __restrict__ soff,
                              int* __restrict__ ssrc,
                              const int* __restrict__ sn, const int* __restrict__ se,
                              const int* __restrict__ kn, const int* __restrict__ ke,
                              int* __restrict__ hoff, int* __restrict__ pns)
{
    int i = blockIdx.x * blockDim.x + threadIdx.x;
    if (i < DE) {
        int key = et[i] * DN + dst[i];
        int pos = atomicAdd(&soff[key], 1);
        ssrc[pos] = src[i];
    } else {
        int j = i - DE;
        if (j >= 2 * DP) return;
        int e, node;
        if (j < DP) { e = se[j]; node = sn[j]; }
        else { e = DHE + ke[j - DP]; node = kn[j - DP]; }
        int pos = atomicAdd(&hoff[e], 1);
        pns[pos] = node;
    }
}

// one wave per NEEDED hyperedge: efeat[he] = mean of kg[node]; st recomputed from in-place hoff
__global__ void k_hyper_agg(const float* __restrict__ xsrc, const int* __restrict__ pns,
                            const int* __restrict__ hoff, const int* __restrict__ hcnt,
                            const int* __restrict__ heneed, float* __restrict__ efeat)
{
    int lane = threadIdx.x & 63;
    int he = (blockIdx.x * blockDim.x + threadIdx.x) >> 6;
    if (he >= DHE2) return;
    if (!heneed[he]) return;
    int len = hcnt[he];
    int st = hoff[he] - len;   // hoff was incremented in-place during bucketing
    int half = lane >> 5;
    int c16 = (lane & 31) * 4;
    float4 acc = make_float4(0.f, 0.f, 0.f, 0.f);
    int c = 0;
    for (; c + 4 <= len; c += 4) {
        int n0 = pns[st + c + half];
        int n1 = pns[st + c + 2 + half];
        float4 v0 = *(const float4*)&xsrc[(size_t)n0 * 128 + c16];
        float4 v1 = *(const float4*)&xsrc[(size_t)n1 * 128 + c16];
        acc.x += v0.x + v1.x; acc.y += v0.y + v1.y;
        acc.z += v0.z + v1.z; acc.w += v0.w + v1.w;
    }
    for (; c < len; c += 2) {
        int idx = c + half;
        if (idx < len) {
            int n = pns[st + idx];
            float4 v = *(const float4*)&xsrc[(size_t)n * 128 + c16];
            acc.x += v.x; acc.y += v.y; acc.z += v.z; acc.w += v.w;
        }
    }
    acc.x += __shfl_xor(acc.x, 32);
    acc.y += __shfl_xor(acc.y, 32);
    acc.z += __shfl_xor(acc.z, 32);
    acc.w += __shfl_xor(acc.w, 32);
    if (half == 0) {
        float inv = (len > 0) ? 1.0f / (float)len : 0.f;
        float4 o = make_float4(acc.x * inv, acc.y * inv, acc.z * inv, acc.w * inv);
        *(float4*)&efeat[(size_t)he * 128 + c16] = o;
    }
}

__global__ void k_slot_assign2(const int* __restrict__ sidx, const int* __restrict__ kidx,
                               int* slot_s, int* slot_k, int* scnt)
{
    int i = blockIdx.x * blockDim.x + threadIdx.x;
    if (i < DB * DLR) {
        int node = sidx[i];
        if (atomicCAS(&slot_s[node], -1, -2) == -1) slot_s[node] = atomicAdd(&scnt[0], 1);
    } else if (i < 2 * DB * DLR) {
        int node = kidx[i - DB * DLR];
        if (atomicCAS(&slot_k[node], -1, -2) == -1) slot_k[node] = atomicAdd(&scnt[1], 1);
    }
}

// fused sdeg + match + need-flag, block-aggregated compaction
__global__ __launch_bounds__(256) void k_sdeg_match(
    const int* __restrict__ nodes, const int* __restrict__ he, const int* __restrict__ slot,
    float* sdeg, int* mcnt, int* mhe, int* msl, int* heneed, int heBase)
{
    __shared__ int lcnt, lbase;
    if (threadIdx.x == 0) lcnt = 0;
    __syncthreads();
    int i = blockIdx.x * 256 + threadIdx.x;
    int s = -1, lidx = 0, h = 0;
    if (i < DP) {
        s = slot[nodes[i]];
        if (s >= 0) {
            h = heBase + he[i];
            heneed[h] = 1;
            atomicAdd(&sdeg[s], 1.0f);
            lidx = atomicAdd(&lcnt, 1);
        }
    }
    __syncthreads();
    if (threadIdx.x == 0) lbase = (lcnt > 0) ? atomicAdd(mcnt, lcnt) : 0;
    __syncthreads();
    if (s >= 0) {
        int idx = lbase + lidx;
        if (idx < MCAP) { mhe[idx] = h; msl[idx] = s; }
    }
}

// both sides in one launch
__global__ void k_accmatch2(const float* __restrict__ efeat,
                            const int* __restrict__ mhe_s, const int* __restrict__ msl_s,
                            const int* __restrict__ mhe_k, const int* __restrict__ msl_k,
                            const int* __restrict__ mcnt,
                            float* sacc_s, float* sacc_k)
{
    int lane = threadIdx.x & 63;
    int w = (blockIdx.x * blockDim.x + threadIdx.x) >> 6;
    int nw = (gridDim.x * blockDim.x) >> 6;
    int Ms = min(mcnt[0], MCAP), Mk = min(mcnt[1], MCAP);
    for (int i = w; i < Ms + Mk; i += nw) {
        bool sess = i < Ms;
        int he = sess ? mhe_s[i] : mhe_k[i - Ms];
        int sl = sess ? msl_s[i] : msl_k[i - Ms];
        float* sacc = sess ? sacc_s : sacc_k;
        float2 v = *(const float2*)&efeat[(size_t)he * 128 + lane * 2];
        atomicAdd(&sacc[(size_t)sl * 128 + lane * 2],     v.x);
        atomicAdd(&sacc[(size_t)sl * 128 + lane * 2 + 1], v.y);
    }
}

// both sides in one launch
__global__ void k_rel_gather2(const float* __restrict__ so_s, const float* __restrict__ so_k,
                              const int* __restrict__ slot_s, const int* __restrict__ slot_k,
                              const int* __restrict__ ridx_s, const int* __restrict__ ridx_k,
                              float* __restrict__ related)
{
    int gid = blockIdx.x * blockDim.x + threadIdx.x;
    int i = gid >> 5, c = gid & 31;
    if (i >= 2 * DB * DLR) return;
    bool sess = i < DB * DLR;
    int ii = sess ? i : i - DB * DLR;
    int s = sess ? slot_s[ridx_s[ii]] : slot_k[ridx_k[ii]];
    const float* so = sess ? so_s : so_k;
    int b = ii / DLR, l = ii % DLR;
    int colOff = sess ? 0 : 64;
    ((float4*)&related[((size_t)b * 128 + colOff + l) * 128])[c] =
        ((const float4*)&so[(size_t)s * 128])[c];
}

// ---------------------------------------------------------------- MHA: one block per (b,h)
__global__ __launch_bounds__(256) void k_mha(const float* __restrict__ qb,
                                             const float* __restrict__ kb,
                                             const float* __restrict__ vb,
                                             float* __restrict__ ob)
{
    int b = blockIdx.x >> 3, h = blockIdx.x & 7;
    __shared__ float Ks[128][16], Vs[128][16], Qs[32][16];
    int tid = threadIdx.x;
    for (int i = tid; i < 128 * 16; i += 256) {
        int j = i >> 4, d = i & 15;
        Ks[j][d] = kb[((size_t)b * 128 + j) * 128 + h * 16 + d];
        Vs[j][d] = vb[((size_t)b * 128 + j) * 128 + h * 16 + d];
    }
    for (int i = tid; i < 32 * 16; i += 256) {
        int q = i >> 4, d = i & 15;
        Qs[q][d] = qb[((size_t)b * 32 + q) * 128 + h * 16 + d] * 0.25f;
    }
    __syncthreads();
    int q = tid >> 3;
    int jg = tid & 7;
    float lg[16];
    float m = -1e30f;
    #pragma unroll
    for (int jj = 0; jj < 16; ++jj) {
        int j = jg * 16 + jj;
        float s = 0.f;
        #pragma unroll
        for (int d = 0; d < 16; ++d) s += Qs[q][d] * Ks[j][d];
        lg[jj] = s;
        m = fmaxf(m, s);
    }
    #pragma unroll
    for (int o = 1; o < 8; o <<= 1) m = fmaxf(m, __shfl_xor(m, o));
    float sum = 0.f;
    float acc[16] = {};
    #pragma unroll
    for (int jj = 0; jj < 16; ++jj) {
        float p = __expf(lg[jj] - m);
        sum += p;
        int j = jg * 16 + jj;
        #pragma unroll
        for (int d = 0; d < 16; ++d) acc[d] += p * Vs[j][d];
    }
    #pragma unroll
    for (int o = 1; o < 8; o <<= 1) {
        sum += __shfl_xor(sum, o);
        #pragma unroll
        for (int d = 0; d < 16; ++d) acc[d] += __shfl_xor(acc[d], o);
    }
    if (jg == 0) {
        float inv = 1.0f / sum;
        #pragma unroll
        for (int d = 0; d < 16; ++d)
            ob[((size_t)b * 32 + q) * 128 + h * 16 + d] = acc[d] * inv;
    }
}

// ---------------------------------------------------------------- launch
extern "C" void kernel_launch(void* const* d_in, const int* in_sizes, int n_in,
                              void* d_out, int out_size, void* d_ws, size_t ws_size,
                              hipStream_t stream)
{
    const float* emb        = (const float*)d_in[0];
    const float* bases      = (const float*)d_in[1];
    const float* comp       = (const float*)d_in[2];
    const float* root       = (const float*)d_in[3];
    const float* rgcn_bias  = (const float*)d_in[4];
    const float* sess_theta = (const float*)d_in[5];
    const float* sess_bias  = (const float*)d_in[6];
    const float* know_theta = (const float*)d_in[7];
    const float* know_bias  = (const float*)d_in[8];
    const float* in_proj_w  = (const float*)d_in[9];
    const float* in_proj_b  = (const float*)d_in[10];
    const float* out_proj_w = (const float*)d_in[11];
    const float* out_proj_b = (const float*)d_in[12];
    const float* attn_his_a = (const float*)d_in[13];
    const float* attn_his_b = (const float*)d_in[14];
    const float* attn_a     = (const float*)d_in[15];
    const float* attn_b     = (const float*)d_in[16];
    const float* rec_bias   = (const float*)d_in[17];
    const int* edge_src     = (const int*)d_in[18];
    const int* edge_dst     = (const int*)d_in[19];
    const int* edge_type    = (const int*)d_in[20];
    const int* sess_nodes   = (const int*)d_in[21];
    const int* sess_edges   = (const int*)d_in[22];
    const int* know_nodes   = (const int*)d_in[23];
    const int* know_edges   = (const int*)d_in[24];
    const int* sess_rel_idx = (const int*)d_in[25];
    const int* know_rel_idx = (const int*)d_in[26];
    const int* context_idx  = (const int*)d_in[27];
    float* out = (float*)d_out;

    float* wsf = (float*)d_ws;
    size_t off = 0;
    auto alloc = [&](size_t n) { size_t r = off; off += (n + 255) & ~(size_t)255; return r; };
    float* kg      = wsf + alloc(12800000);          // N*D
    float* tmp     = wsf + alloc(12800000);          // RGCN sort arena + efeat + split arenas tail
    ushortT* warena = (ushortT*)(wsf + alloc(196608)); // 12 x 64KB split w[r]
    int*   bsumV   = (int*)(wsf + alloc(2048));
    int*   bsumP   = (int*)(wsf + alloc(2048));
    int*   stybase = (int*)(wsf + alloc(16));
    int*   bo      = (int*)(wsf + alloc(16));
    // ---- contiguous zero block (one memset) ----
    size_t zstart = off;
    int*   hhist   = (int*)(wsf + alloc(DHE2));
    int*   heneed  = (int*)(wsf + alloc(DHE2));
    int*   mcnt    = (int*)(wsf + alloc(16));        // [0]=sess, [1]=know
    int*   scnt    = (int*)(wsf + alloc(16));
    float* sdeg_s  = wsf + alloc(4096);
    float* sdeg_k  = wsf + alloc(4096);
    float* sacc_s  = wsf + alloc(524288);
    float* sacc_k  = wsf + alloc(524288);
    size_t zend = off;
    // ---- contiguous 0xFF block (one memset) ----
    size_t fstart = off;
    int*   slot_s  = (int*)(wsf + alloc(100000));
    int*   slot_k  = (int*)(wsf + alloc(100000));
    size_t fend = off;
    int*   hoff    = (int*)(wsf + alloc(DHE2));
    int*   pns     = (int*)(wsf + alloc(2 * DP));
    int*   mhe_s   = (int*)(wsf + alloc(MCAP));
    int*   msl_s   = (int*)(wsf + alloc(MCAP));
    int*   mhe_k   = (int*)(wsf + alloc(MCAP));
    int*   msl_k   = (int*)(wsf + alloc(MCAP));
    float* so_s    = wsf + alloc(524288);
    float* so_k    = wsf + alloc(524288);
    float* related = wsf + alloc(1048576);
    float* ctx     = wsf + alloc(262144);
    float* qb      = wsf + alloc(262144);
    float* kb      = wsf + alloc(1048576);
    float* vb      = wsf + alloc(1048576);
    float* obuf    = wsf + alloc(262144);
    float* attrel  = wsf + alloc(262144);
    float* his     = wsf + alloc(8192);
    float* ucat    = wsf + alloc(270336);
    float* userb   = wsf + alloc(8192);
    float* e1      = wsf + alloc(2048);
    float* e2      = wsf + alloc(2112);
    (void)ws_size; (void)in_sizes; (void)n_in; (void)out_size;

    // RGCN sort arena inside tmp; efeat + split arenas in the tail
    int*   hist    = (int*)tmp;                 // 1.2M ints
    int*   soff    = (int*)tmp + 1200000;       // 1.2M (in-place cursor during bucket)
    int*   segpos  = (int*)tmp + 2400000;       // 1.2M
    int*   seglist = (int*)tmp + 3600000;       // 1.2M
    int*   ssrc    = (int*)tmp + 4800000;       // 1.0M
    float* efeat   = tmp + 6000000;             // 5.12M (used only after RGCN finishes)
    ushortT* wsplit = (ushortT*)(tmp + 12200000); // 9 x 32768 ushorts
    ushortT* usplit = (ushortT*)(tmp + 12400000); // 16384 ushorts

    const int nbR = (NRBINS + SCAN_CHUNK - 1) / SCAN_CHUNK;   // 1172
    const int nbH = (DHE2 + SCAN_CHUNK - 1) / SCAN_CHUNK;     // 40

    // ---------------- upfront memsets (3 total)
    hipMemsetAsync(wsf + zstart, 0, (zend - zstart) * 4, stream);
    hipMemsetAsync(wsf + fstart, 0xFF, (fend - fstart) * 4, stream);
    hipMemsetAsync(hist, 0, (size_t)NRBINS * 4, stream);

    // weight pre-split (independent of everything else)
    k_presplit_all<<<576, 256, 0, stream>>>(root, sess_theta, know_theta, in_proj_w,
                                            out_proj_w, attn_his_a, attn_a, wsplit);

    k_slot_assign2<<<32, 256, 0, stream>>>(sess_rel_idx, know_rel_idx, slot_s, slot_k, scnt);
    k_sdeg_match<<<(DP + 255) / 256, 256, 0, stream>>>(sess_nodes, sess_edges, slot_s,
                                                       sdeg_s, mcnt, mhe_s, msl_s, heneed, 0);
    k_sdeg_match<<<(DP + 255) / 256, 256, 0, stream>>>(know_nodes, know_edges, slot_k,
                                                       sdeg_k, mcnt + 1, mhe_k, msl_k, heneed, DHE);

    // ---------------- histograms (RGCN + hyper in one launch)
    k_hist_both<<<(DE + 2 * DP + 255) / 256, 256, 0, stream>>>(edge_dst, edge_type, hist,
                                                               sess_edges, know_edges, hhist);
    // RGCN scans
    k_scan2_pass1<<<nbR, 256, 0, stream>>>(hist, NRBINS, bsumV, bsumP);
    k_scan2_pass2<<<1, 256, 0, stream>>>(bsumV, bsumP, nbR, stybase + DR);
    k_scan2_pass3<<<nbR, 256, 0, stream>>>(hist, NRBINS, bsumV, bsumP, soff, segpos);
    // hyper scan
    k_scan_pass1<<<nbH, 256, 0, stream>>>(hhist, DHE2, bsumV);
    k_scan_pass2p<<<1, 256, 0, stream>>>(bsumV, nbH, nullptr);
    k_scan_pass3<<<nbH, 256, 0, stream>>>(hhist, DHE2, bsumV, hoff);

    k_stypebase<<<1, 64, 0, stream>>>(segpos, stybase, bo);
    k_seglist<<<(NRBINS + 255) / 256, 256, 0, stream>>>(hist, segpos, seglist, NRBINS);

    // ---------------- bucket scatters (RGCN + hyper in one launch, in-place cursors)
    k_bucket_both<<<(DE + 2 * DP + 255) / 256, 256, 0, stream>>>(
        edge_src, edge_dst, edge_type, soff, ssrc,
        sess_nodes, sess_edges, know_nodes, know_edges, hoff, pns);

    k_wcomp_split<<<(DR * DD * DD + 255) / 256, 256, 0, stream>>>(comp, bases, warena);

    int gemmN = (DN + 63) / 64;
    k_gemm_ds<<<gemmN, 256, 0, stream>>>(emb, wsplit + 0 * 32768, rgcn_bias, nullptr,
                                         nullptr, nullptr, kg, DN);
    // all 12 relations in one launch (upper-bound grid; excess blocks exit on bo[DR])
    k_rgcn_all<<<(DE + 63) / 64 + DR, 256, 0, stream>>>(emb, warena, seglist, soff, hist,
                                                        ssrc, stybase, bo, kg);

    // ---------------- hypergraph aggregation
    k_hyper_agg<<<(DHE2 * 64 + 255) / 256, 256, 0, stream>>>(kg, pns, hoff, hhist, heneed, efeat);
    k_accmatch2<<<256, 256, 0, stream>>>(efeat, mhe_s, msl_s, mhe_k, msl_k, mcnt, sacc_s, sacc_k);

    k_gemm_ds<<<64, 256, 0, stream>>>(sacc_s, wsplit + 1 * 32768, sess_bias, sdeg_s,
                                      nullptr, nullptr, so_s, 4096);
    k_gemm_ds<<<64, 256, 0, stream>>>(sacc_k, wsplit + 2 * 32768, know_bias, sdeg_k,
                                      nullptr, nullptr, so_k, 4096);
    k_rel_gather2<<<(2 * DB * DLR * 32 + 255) / 256, 256, 0, stream>>>(
        so_s, so_k, slot_s, slot_k, sess_rel_idx, know_rel_idx, related);

    // ---------------- context + MHA (q-GEMM gathers ctx rows from kg and writes ctx)
    k_gemm_ds<<<(DB * DLC + 63) / 64, 256, 0, stream>>>(kg, wsplit + 3 * 32768,
                                                        in_proj_b, nullptr,
                                                        context_idx, ctx, qb, DB * DLC);
    k_gemm_ds<<<(DB * 128 + 63) / 64, 256, 0, stream>>>(related, wsplit + 4 * 32768,
                                                        in_proj_b + DD, nullptr,
                                                        nullptr, nullptr, kb, DB * 128);
    k_gemm_ds<<<(DB * 128 + 63) / 64, 256, 0, stream>>>(related, wsplit + 5 * 32768,
                                                        in_proj_b + 2 * DD, nullptr,
                                                        nullptr, nullptr, vb, DB * 128);
    k_mha<<<DB * DNH, 256, 0, stream>>>(qb, kb, vb, obuf);
    k_gemm_ds<<<(DB * DLC + 63) / 64, 256, 0, stream>>>(obuf, wsplit + 6 * 32768,
                                                        out_proj_b, nullptr,
                                                        nullptr, nullptr, attrel, DB * DLC);

    // ---------------- pooling (GEMM-shaped) + score
    k_tanh_dot_ds<<<(DB * DLC + 63) / 64, 256, 0, stream>>>(attrel, wsplit + 7 * 32768,
                                                            attn_his_b, e1, DB * DLC);
    k_pool_apply<32><<<DB, 128, 0, stream>>>(attrel, e1, his, nullptr);
    k_build_ucat<<<(DB * 33 * 128 + 255) / 256, 256, 0, stream>>>(ctx, his, ucat);
    k_tanh_dot_ds<<<(DB * 33 + 63) / 64, 256, 0, stream>>>(ucat, wsplit + 8 * 32768,
                                                           attn_b, e2, DB * 33);
    k_pool_apply<33><<<DB, 128, 0, stream>>>(ucat, e2, userb, usplit);
    k_score_ds<<<gemmN, 256, 0, stream>>>(kg, usplit, rec_bias, out);
}